// Round 16
// baseline (440.120 us; speedup 1.0000x reference)
//
#include <hip/hip_runtime.h>

namespace {

typedef __attribute__((ext_vector_type(8))) short short8v;
typedef __attribute__((ext_vector_type(4))) float f32x4;
typedef __attribute__((ext_vector_type(4))) unsigned int uint4v;

constexpr int kB = 8;
constexpr int kS = 1024;
constexpr int kSUB = 768;
constexpr int kL = 4096;                                   // P*G
constexpr float kQScale = 0.25f * 1.44269504088896340736f; // SCALING*log2(e)
constexpr float kLamInit = 0.2f;
constexpr float kOutScale = 0.8f;
constexpr float kShift = 64.f;  // fixed softmax shift (log2 units); |score|<<60

__device__ __forceinline__ unsigned short f2bf(float x) {
  unsigned u = __float_as_uint(x);
  return (unsigned short)((u + 0x7FFFu + ((u >> 16) & 1u)) >> 16);
}

__device__ __forceinline__ float fast_exp2(float x) {
#if __has_builtin(__builtin_amdgcn_exp2f)
  return __builtin_amdgcn_exp2f(x);
#else
  return exp2f(x);
#endif
}

__device__ __forceinline__ int load_mask(const void* p, long i, int fmt) {
  if (fmt == 1) return (int)((const unsigned char*)p)[i];
  if (fmt == 2) return (int)(((const int*)p)[2 * i] != 0);
  return ((const int*)p)[i];
}

// ---------------------------------------------------------------------------
// prep: blocks 0..191 transpose Wk/Wv to bf16 [c][k]; block 192 detects mask
// layout (0=int32,1=u8,2=int64).
// ---------------------------------------------------------------------------
__global__ __launch_bounds__(256) void prep_kernel(
    const float* __restrict__ Wk, const float* __restrict__ Wv,
    const unsigned char* __restrict__ qm, unsigned short* __restrict__ WkT,
    unsigned short* __restrict__ WvT, int* __restrict__ flag) {
  if (blockIdx.x < 192) {
    int idx = blockIdx.x * 256 + threadIdx.x;
    if (idx < 24576) {
      const int k = idx >> 5, c = idx & 31;
      WkT[c * 768 + k] = f2bf(Wk[idx]);
    } else {
      idx -= 24576;
      const int k = idx >> 5, c = idx & 31;
      WvT[c * 768 + k] = f2bf(Wv[idx]);
    }
  } else {
    __shared__ int any14, any47;
    if (threadIdx.x == 0) { any14 = 0; any47 = 0; }
    __syncthreads();
    int l14 = 0, l47 = 0;
    for (int i = threadIdx.x; i < 16384; i += 256) {
      const unsigned char v = qm[i];
      if (v && (i & 3)) l14 = 1;
      if (v && ((i & 7) >= 4)) l47 = 1;
    }
    if (l14) atomicOr(&any14, 1);
    if (l47) atomicOr(&any47, 1);
    __syncthreads();
    if (threadIdx.x == 0) *flag = any14 ? 1 : (any47 ? 0 : 2);
  }
}

// ---------------------------------------------------------------------------
// K/V projection, split-K: 32 rows/block, 256 threads (4 waves).
// ---------------------------------------------------------------------------
__global__ __launch_bounds__(256) void proj_kv_kernel(
    const float* __restrict__ key, const unsigned short* __restrict__ WkT,
    const unsigned short* __restrict__ WvT, unsigned short* __restrict__ Kbf,
    unsigned short* __restrict__ Vt) {
  __shared__ float comb[2][64][20];
  const int t = threadIdx.x;
  const int wv = t >> 6, lane = t & 63;
  const int r15 = lane & 15, g = lane >> 4;
  const int grp = wv >> 1;
  const int half = wv & 1;
  const int row = blockIdx.x * 32 + grp * 16 + r15;
  const int kbase = half * 384;
  const float* kp = &key[(size_t)row * kSUB + kbase];
  const f32x4 zf = {0.f, 0.f, 0.f, 0.f};
  f32x4 aK0 = zf, aK1 = zf, aV0 = zf, aV1 = zf;
#pragma unroll 4
  for (int ks = 0; ks < 384; ks += 32) {
    const f32x4 lo = *(const f32x4*)&kp[ks + g * 8];
    const f32x4 hi = *(const f32x4*)&kp[ks + g * 8 + 4];
    short8v a;
#pragma unroll
    for (int j = 0; j < 4; ++j) {
      a[j] = (short)f2bf(lo[j]);
      a[4 + j] = (short)f2bf(hi[j]);
    }
    const int ko = kbase + ks + g * 8;
    const short8v bk0 = *(const short8v*)&WkT[(size_t)r15 * 768 + ko];
    const short8v bk1 = *(const short8v*)&WkT[(size_t)(16 + r15) * 768 + ko];
    const short8v bv0 = *(const short8v*)&WvT[(size_t)r15 * 768 + ko];
    const short8v bv1 = *(const short8v*)&WvT[(size_t)(16 + r15) * 768 + ko];
    aK0 = __builtin_amdgcn_mfma_f32_16x16x32_bf16(a, bk0, aK0, 0, 0, 0);
    aK1 = __builtin_amdgcn_mfma_f32_16x16x32_bf16(a, bk1, aK1, 0, 0, 0);
    aV0 = __builtin_amdgcn_mfma_f32_16x16x32_bf16(a, bv0, aV0, 0, 0, 0);
    aV1 = __builtin_amdgcn_mfma_f32_16x16x32_bf16(a, bv1, aV1, 0, 0, 0);
  }
  if (half == 1) {
    *(f32x4*)&comb[grp][lane][0] = aK0;
    *(f32x4*)&comb[grp][lane][4] = aK1;
    *(f32x4*)&comb[grp][lane][8] = aV0;
    *(f32x4*)&comb[grp][lane][12] = aV1;
  }
  __syncthreads();
  if (half == 0) {
    aK0 += *(const f32x4*)&comb[grp][lane][0];
    aK1 += *(const f32x4*)&comb[grp][lane][4];
    aV0 += *(const f32x4*)&comb[grp][lane][8];
    aV1 += *(const f32x4*)&comb[grp][lane][12];
    const int orow = blockIdx.x * 32 + grp * 16 + g * 4;
#pragma unroll
    for (int jj = 0; jj < 4; ++jj) {
      const int r = orow + jj;
      Kbf[(size_t)r * 32 + r15] = f2bf(aK0[jj]);
      Kbf[(size_t)r * 32 + 16 + r15] = f2bf(aK1[jj]);
      const int bb = r >> 10, s = r & 1023;
      Vt[((size_t)bb * 32 + r15) * kS + s] = f2bf(aV0[jj]);
      Vt[((size_t)bb * 32 + 16 + r15) * kS + s] = f2bf(aV1[jj]);
    }
  }
}

// ---------------------------------------------------------------------------
// Fused attention, wave-owns-full-row: each of 8 waves owns 16 q-rows over
// the full S=1024. Pass A: sums. Pass B: d + row-min, caching bf16(d) in
// 128 VGPRs. Pass C: unpack d -> diff stores + PV (no QK recompute).
// No barriers/atomics/cross-wave traffic in the worker loop. 256 blocks.
// ---------------------------------------------------------------------------
__global__ __launch_bounds__(512, 2) void attn_kernel(
    const float* __restrict__ query, const float* __restrict__ Wq,
    const unsigned short* __restrict__ Kbf,
    const unsigned short* __restrict__ Vt, const void* __restrict__ qmask,
    const void* __restrict__ kmask, const float* __restrict__ lq1,
    const float* __restrict__ lk1, const float* __restrict__ lq2,
    const float* __restrict__ lk2, const float* __restrict__ rmsw,
    const float* __restrict__ Wo, const int* __restrict__ mflag,
    float* __restrict__ out, float* __restrict__ diff) {
  extern __shared__ __align__(16) unsigned short kfl[];  // [1024][40] 80KB

  __shared__ __align__(16) float ubuf[5120];  // {sWq 1K + sQi 4K} | nxlds
  __shared__ __align__(16) unsigned short qlds[128][40];
  __shared__ unsigned kmp_lds[256];
  __shared__ float sWo[32][32];
  __shared__ float srw[32];
  __shared__ int qmS[128];
  __shared__ float slam;

  float* const sWq = ubuf;
  float* const sQi = ubuf + 1024;
  float* const nxlds = ubuf;  // overlays sWq/sQi after the qproj barrier

  const int t = threadIdx.x;
  const int lane = t & 63;
  const int w = t >> 6;
  const int r15 = lane & 15;
  const int g = lane >> 4;
  const int b = blockIdx.x >> 5;
  const int rowbase = b * kL + (blockIdx.x & 31) * 128;
  const int kvb = b * kS;
  const int fmt = *mflag;

  // ---- stage (once per 128 rows) ----
  if (t < 256) {
    *(f32x4*)(sWq + 4 * t) = *(const f32x4*)(Wq + 4 * t);
    *(f32x4*)(&sWo[0][0] + 4 * t) = *(const f32x4*)(Wo + 4 * t);
    const long base = (long)kvb + 4 * t;
    const unsigned m0 = load_mask(kmask, base + 0, fmt) ? 1u : 0u;
    const unsigned m1 = load_mask(kmask, base + 1, fmt) ? 1u : 0u;
    const unsigned m2 = load_mask(kmask, base + 2, fmt) ? 1u : 0u;
    const unsigned m3 = load_mask(kmask, base + 3, fmt) ? 1u : 0u;
    kmp_lds[t] = m0 | (m1 << 8) | (m2 << 16) | (m3 << 24);
  }
  *(f32x4*)(sQi + 8 * t) = *(const f32x4*)(query + (size_t)rowbase * 32 + 8 * t);
  *(f32x4*)(sQi + 8 * t + 4) =
      *(const f32x4*)(query + (size_t)rowbase * 32 + 8 * t + 4);
#pragma unroll
  for (int p = 0; p < 8; ++p) {
    const int i = t + 512 * p;  // 0..4095: (row, quarter)
    const int row = i >> 2, qtr = i & 3;
    *(short8v*)&kfl[row * 40 + qtr * 8] =
        *(const short8v*)&Kbf[((size_t)(kvb + row)) * 32 + qtr * 8];
  }
  if (t < 128) qmS[t] = load_mask(qmask, (long)rowbase + t, fmt);
  if (t < 32) srw[t] = rmsw[t];
  if (t == 0) {
    float a = 0.f, c2 = 0.f;
#pragma unroll
    for (int i = 0; i < 16; ++i) {
      a += lq1[i] * lk1[i];
      c2 += lq2[i] * lk2[i];
    }
    slam = expf(a) - expf(c2) + kLamInit;
  }
  __syncthreads();

  // ---- fused Q projection: qlds[q][e] = bf16(dot * scale), 128 rows ----
#pragma unroll
  for (int p = 0; p < 8; ++p) {
    const int idx = t + 512 * p;
    const int row = idx >> 5, col = idx & 31;
    float a = 0.f;
#pragma unroll
    for (int k = 0; k < 32; ++k) a += sQi[row * 32 + k] * sWq[k * 32 + col];
    qlds[row][col] = f2bf(a * kQScale);
  }
  __syncthreads();  // last barrier; worker loop below is barrier-free

  const short8v z8 = {0, 0, 0, 0, 0, 0, 0, 0};
  const f32x4 zf = {0.f, 0.f, 0.f, 0.f};
  const float lam = slam;
  const int qm = qmS[w * 16 + r15];
  const int wrow = rowbase + w * 16;  // this wave's first q-row

  short8v qa0 = z8, qa1 = z8;
  if (lane < 32) {
    qa0 = *(const short8v*)&qlds[w * 16 + r15][g * 8];
    qa1 = *(const short8v*)&qlds[w * 16 + r15][16 + g * 8];
  }

  // ---- PASS A: sum of exp2(score - 64) per (q,head), full S ----
  f32x4 s0v = zf, s1v = zf;
  for (int sl = 0; sl < 8; ++sl) {
#pragma unroll
    for (int c = 0; c < 8; ++c) {
      const int srow = sl * 128 + c * 16 + r15;
      short8v kb0 = z8, kb1 = z8;
      if (lane < 32) {
        kb0 = *(const short8v*)&kfl[srow * 40 + g * 8];
        kb1 = *(const short8v*)&kfl[srow * 40 + 16 + g * 8];
      }
      const f32x4 a0 =
          __builtin_amdgcn_mfma_f32_16x16x32_bf16(kb0, qa0, zf, 0, 0, 0);
      const f32x4 a1 =
          __builtin_amdgcn_mfma_f32_16x16x32_bf16(kb1, qa1, zf, 0, 0, 0);
      const unsigned km = kmp_lds[sl * 32 + c * 4 + g];
#pragma unroll
      for (int jj = 0; jj < 4; ++jj) {
        const int mbit = (km >> (8 * jj)) & 1u;
        s0v[jj] += mbit ? fast_exp2(a0[jj] - kShift) : 0.f;
        s1v[jj] += mbit ? fast_exp2(a1[jj] - kShift) : 0.f;
      }
    }
  }
  float s0 = (s0v[0] + s0v[1]) + (s0v[2] + s0v[3]);
  float s1 = (s1v[0] + s1v[1]) + (s1v[2] + s1v[3]);
  s0 += __shfl_xor(s0, 16);
  s0 += __shfl_xor(s0, 32);
  s1 += __shfl_xor(s1, 16);
  s1 += __shfl_xor(s1, 32);
  const float f0 = 1.f / (s0 + 1e-37f);
  const float nf1 = -lam / (s1 + 1e-37f);

  // ---- PASS B: d + row-min; cache bf16(d) packed in regs ----
  unsigned dpx[8][8], dpy[8][8];
  f32x4 dmn = {3.0e38f, 3.0e38f, 3.0e38f, 3.0e38f};
#pragma unroll
  for (int sl = 0; sl < 8; ++sl) {
#pragma unroll
    for (int c = 0; c < 8; ++c) {
      const int srow = sl * 128 + c * 16 + r15;
      short8v kb0 = z8, kb1 = z8;
      if (lane < 32) {
        kb0 = *(const short8v*)&kfl[srow * 40 + g * 8];
        kb1 = *(const short8v*)&kfl[srow * 40 + 16 + g * 8];
      }
      const f32x4 a0 =
          __builtin_amdgcn_mfma_f32_16x16x32_bf16(kb0, qa0, zf, 0, 0, 0);
      const f32x4 a1 =
          __builtin_amdgcn_mfma_f32_16x16x32_bf16(kb1, qa1, zf, 0, 0, 0);
      const unsigned km = kmp_lds[sl * 32 + c * 4 + g];
      f32x4 d;
#pragma unroll
      for (int jj = 0; jj < 4; ++jj) {
        const int mbit = (km >> (8 * jj)) & 1u;
        const float e0 = mbit ? fast_exp2(a0[jj] - kShift) : 0.f;
        const float e1 = mbit ? fast_exp2(a1[jj] - kShift) : 0.f;
        d[jj] = fmaf(e0, f0, nf1 * e1);
        dmn[jj] = fminf(dmn[jj], d[jj]);
      }
      dpx[sl][c] = (unsigned)f2bf(d[0]) | ((unsigned)f2bf(d[1]) << 16);
      dpy[sl][c] = (unsigned)f2bf(d[2]) | ((unsigned)f2bf(d[3]) << 16);
    }
  }
  float dm = fminf(fminf(dmn[0], dmn[1]), fminf(dmn[2], dmn[3]));
  dm = fminf(dm, __shfl_xor(dm, 16));
  dm = fminf(dm, __shfl_xor(dm, 32));
  const float rme = dm - 1e-5f;  // rmin - eps

  // ---- PASS C: unpack d -> diff stores + PV (no QK recompute) ----
  f32x4 pv0 = zf, pv1 = zf;
  const int sl0 = ((g & 1) << 5) + r15;  // PV gather source lanes
  const int sl1 = sl0 + 16;
  const bool hi = (g >> 1) != 0;
#pragma unroll
  for (int sl = 0; sl < 8; ++sl) {
    short8v vt0[4], vt1[4];
#pragma unroll
    for (int kc = 0; kc < 4; ++kc) {
      const int soff = sl * 128 + kc * 32 + g * 8;
      vt0[kc] = *(const short8v*)&Vt[((size_t)(b * 32 + r15)) * kS + soff];
      vt1[kc] = *(const short8v*)&Vt[((size_t)(b * 32 + 16 + r15)) * kS + soff];
    }
    unsigned pkx[8], pky[8];
#pragma unroll
    for (int c = 0; c < 8; ++c) {
      const unsigned km = kmp_lds[sl * 32 + c * 4 + g];
      const unsigned px = dpx[sl][c], py = dpy[sl][c];
      const float d0 = __uint_as_float(px << 16);
      const float d1 = __uint_as_float(px & 0xFFFF0000u);
      const float d2 = __uint_as_float(py << 16);
      const float d3 = __uint_as_float(py & 0xFFFF0000u);
      f32x4 fd;
      fd[0] = (qm && (km & 1u)) ? d0 - rme : 0.f;
      fd[1] = (qm && ((km >> 8) & 1u)) ? d1 - rme : 0.f;
      fd[2] = (qm && ((km >> 16) & 1u)) ? d2 - rme : 0.f;
      fd[3] = (qm && ((km >> 24) & 1u)) ? d3 - rme : 0.f;
      *(f32x4*)&diff[((size_t)(wrow + r15)) * kS + sl * 128 + c * 16 + g * 4] =
          fd;
      pkx[c] = (unsigned)f2bf(fd[0]) | ((unsigned)f2bf(fd[1]) << 16);
      pky[c] = (unsigned)f2bf(fd[2]) | ((unsigned)f2bf(fd[3]) << 16);
    }
    // PV gather: broadcast both chunk parities; DEST selects with hi
#pragma unroll
    for (int kc = 0; kc < 4; ++kc) {
      const unsigned x0a = (unsigned)__shfl((int)pkx[2 * kc], sl0);
      const unsigned y0a = (unsigned)__shfl((int)pky[2 * kc], sl0);
      const unsigned x0b = (unsigned)__shfl((int)pkx[2 * kc], sl1);
      const unsigned y0b = (unsigned)__shfl((int)pky[2 * kc], sl1);
      const unsigned x1a = (unsigned)__shfl((int)pkx[2 * kc + 1], sl0);
      const unsigned y1a = (unsigned)__shfl((int)pky[2 * kc + 1], sl0);
      const unsigned x1b = (unsigned)__shfl((int)pkx[2 * kc + 1], sl1);
      const unsigned y1b = (unsigned)__shfl((int)pky[2 * kc + 1], sl1);
      uint4v avw;
      avw.x = hi ? x1a : x0a;
      avw.y = hi ? y1a : y0a;
      avw.z = hi ? x1b : x0b;
      avw.w = hi ? y1b : y0b;
      const short8v av = *(const short8v*)&avw;
      pv0 = __builtin_amdgcn_mfma_f32_16x16x32_bf16(av, vt0[kc], pv0, 0, 0, 0);
      pv1 = __builtin_amdgcn_mfma_f32_16x16x32_bf16(av, vt1[kc], pv1, 0, 0, 0);
    }
  }

  // ---- epilogue (per wave): RMSNorm + @Wo ----
  // pv0[jj] = O[q = g*4+jj][e = r15]; pv1[jj] = O[q][e = 16+r15]
  float* const nxw = nxlds + w * (16 * 36);
#pragma unroll
  for (int jj = 0; jj < 4; ++jj) {
    float ss = pv0[jj] * pv0[jj] + pv1[jj] * pv1[jj];
    ss += __shfl_xor(ss, 1);
    ss += __shfl_xor(ss, 2);
    ss += __shfl_xor(ss, 4);
    ss += __shfl_xor(ss, 8);
    const float rms = 1.0f / sqrtf(ss * (1.f / 32.f) + 1e-5f);
    nxw[(g * 4 + jj) * 36 + r15] = pv0[jj] * rms * srw[r15] * kOutScale;
    nxw[(g * 4 + jj) * 36 + 16 + r15] =
        pv1[jj] * rms * srw[16 + r15] * kOutScale;
  }
  asm volatile("s_waitcnt lgkmcnt(0)" ::: "memory");  // own-wave LDS visible

  {
    const int q2 = lane >> 2;
    const int cg = (lane & 3) * 8;
    float o[8] = {0.f, 0.f, 0.f, 0.f, 0.f, 0.f, 0.f, 0.f};
#pragma unroll
    for (int e = 0; e < 32; ++e) {
      const float nv = nxw[q2 * 36 + e];
#pragma unroll
      for (int j = 0; j < 8; ++j) o[j] += nv * sWo[e][cg + j];
    }
    f32x4 olo = {o[0], o[1], o[2], o[3]};
    f32x4 ohi = {o[4], o[5], o[6], o[7]};
    *(f32x4*)&out[((size_t)(wrow + q2)) * 32 + cg] = olo;
    *(f32x4*)&out[((size_t)(wrow + q2)) * 32 + cg + 4] = ohi;
  }
}

}  // namespace

extern "C" void kernel_launch(void* const* d_in, const int* in_sizes, int n_in,
                              void* d_out, int out_size, void* d_ws,
                              size_t ws_size, hipStream_t stream) {
  const float* query = (const float*)d_in[0];
  const float* key = (const float*)d_in[1];
  const void* qmask = d_in[2];
  const void* kmask = d_in[3];
  const float* Wq = (const float*)d_in[4];
  const float* Wk = (const float*)d_in[5];
  const float* Wv = (const float*)d_in[6];
  const float* Wo = (const float*)d_in[7];
  const float* lq1 = (const float*)d_in[8];
  const float* lk1 = (const float*)d_in[9];
  const float* lq2 = (const float*)d_in[10];
  const float* lk2 = (const float*)d_in[11];
  const float* rmsw = (const float*)d_in[12];

  unsigned short* Kbf = (unsigned short*)d_ws;            // [B*S,32]
  unsigned short* Vt = Kbf + (size_t)kB * kS * 32;        // [B,32,S]
  unsigned short* WkT = Vt + (size_t)kB * kS * 32;        // [32,768]
  unsigned short* WvT = WkT + (size_t)32 * 768;           // [32,768]
  int* mflag = (int*)(WvT + (size_t)32 * 768);

  float* outp = (float*)d_out;
  float* diffp = outp + (size_t)kB * kL * 32;

  prep_kernel<<<dim3(193), dim3(256), 0, stream>>>(
      Wk, Wv, (const unsigned char*)qmask, WkT, WvT, mflag);
  proj_kv_kernel<<<dim3(kB * kS / 32), dim3(256), 0, stream>>>(key, WkT, WvT,
                                                               Kbf, Vt);
  attn_kernel<<<dim3(kB * (kL / 128)), dim3(512), 81920, stream>>>(
      query, Wq, Kbf, Vt, qmask, kmask, lq1, lk1, lq2, lk2, rmsw, Wo, mflag,
      outp, diffp);
}

// Round 17
// 392.244 us; speedup vs baseline: 1.1221x; 1.1221x over previous
//
#include <hip/hip_runtime.h>

namespace {

typedef __attribute__((ext_vector_type(8))) short short8v;
typedef __attribute__((ext_vector_type(4))) float f32x4;
typedef __attribute__((ext_vector_type(4))) unsigned int uint4v;

constexpr int kB = 8;
constexpr int kS = 1024;
constexpr int kSUB = 768;
constexpr int kL = 4096;                                   // P*G
constexpr float kQScale = 0.25f * 1.44269504088896340736f; // SCALING*log2(e)
constexpr float kLamInit = 0.2f;
constexpr float kOutScale = 0.8f;
constexpr float kShift = 64.f;  // fixed softmax shift (log2 units); |score|<<60

__device__ __forceinline__ unsigned short f2bf(float x) {
  unsigned u = __float_as_uint(x);
  return (unsigned short)((u + 0x7FFFu + ((u >> 16) & 1u)) >> 16);
}

__device__ __forceinline__ float fast_exp2(float x) {
#if __has_builtin(__builtin_amdgcn_exp2f)
  return __builtin_amdgcn_exp2f(x);
#else
  return exp2f(x);
#endif
}

__device__ __forceinline__ int load_mask(const void* p, long i, int fmt) {
  if (fmt == 1) return (int)((const unsigned char*)p)[i];
  if (fmt == 2) return (int)(((const int*)p)[2 * i] != 0);
  return ((const int*)p)[i];
}

// ---------------------------------------------------------------------------
// prep: blocks 0..191 transpose Wk/Wv to bf16 [c][k]; block 192 detects mask
// layout (0=int32,1=u8,2=int64).
// ---------------------------------------------------------------------------
__global__ __launch_bounds__(256) void prep_kernel(
    const float* __restrict__ Wk, const float* __restrict__ Wv,
    const unsigned char* __restrict__ qm, unsigned short* __restrict__ WkT,
    unsigned short* __restrict__ WvT, int* __restrict__ flag) {
  if (blockIdx.x < 192) {
    int idx = blockIdx.x * 256 + threadIdx.x;
    if (idx < 24576) {
      const int k = idx >> 5, c = idx & 31;
      WkT[c * 768 + k] = f2bf(Wk[idx]);
    } else {
      idx -= 24576;
      const int k = idx >> 5, c = idx & 31;
      WvT[c * 768 + k] = f2bf(Wv[idx]);
    }
  } else {
    __shared__ int any14, any47;
    if (threadIdx.x == 0) { any14 = 0; any47 = 0; }
    __syncthreads();
    int l14 = 0, l47 = 0;
    for (int i = threadIdx.x; i < 16384; i += 256) {
      const unsigned char v = qm[i];
      if (v && (i & 3)) l14 = 1;
      if (v && ((i & 7) >= 4)) l47 = 1;
    }
    if (l14) atomicOr(&any14, 1);
    if (l47) atomicOr(&any47, 1);
    __syncthreads();
    if (threadIdx.x == 0) *flag = any14 ? 1 : (any47 ? 0 : 2);
  }
}

// ---------------------------------------------------------------------------
// K/V projection, split-K: 32 rows/block, 256 threads (4 waves).
// ---------------------------------------------------------------------------
__global__ __launch_bounds__(256) void proj_kv_kernel(
    const float* __restrict__ key, const unsigned short* __restrict__ WkT,
    const unsigned short* __restrict__ WvT, unsigned short* __restrict__ Kbf,
    unsigned short* __restrict__ Vt) {
  __shared__ float comb[2][64][20];
  const int t = threadIdx.x;
  const int wv = t >> 6, lane = t & 63;
  const int r15 = lane & 15, g = lane >> 4;
  const int grp = wv >> 1;
  const int half = wv & 1;
  const int row = blockIdx.x * 32 + grp * 16 + r15;
  const int kbase = half * 384;
  const float* kp = &key[(size_t)row * kSUB + kbase];
  const f32x4 zf = {0.f, 0.f, 0.f, 0.f};
  f32x4 aK0 = zf, aK1 = zf, aV0 = zf, aV1 = zf;
#pragma unroll 4
  for (int ks = 0; ks < 384; ks += 32) {
    const f32x4 lo = *(const f32x4*)&kp[ks + g * 8];
    const f32x4 hi = *(const f32x4*)&kp[ks + g * 8 + 4];
    short8v a;
#pragma unroll
    for (int j = 0; j < 4; ++j) {
      a[j] = (short)f2bf(lo[j]);
      a[4 + j] = (short)f2bf(hi[j]);
    }
    const int ko = kbase + ks + g * 8;
    const short8v bk0 = *(const short8v*)&WkT[(size_t)r15 * 768 + ko];
    const short8v bk1 = *(const short8v*)&WkT[(size_t)(16 + r15) * 768 + ko];
    const short8v bv0 = *(const short8v*)&WvT[(size_t)r15 * 768 + ko];
    const short8v bv1 = *(const short8v*)&WvT[(size_t)(16 + r15) * 768 + ko];
    aK0 = __builtin_amdgcn_mfma_f32_16x16x32_bf16(a, bk0, aK0, 0, 0, 0);
    aK1 = __builtin_amdgcn_mfma_f32_16x16x32_bf16(a, bk1, aK1, 0, 0, 0);
    aV0 = __builtin_amdgcn_mfma_f32_16x16x32_bf16(a, bv0, aV0, 0, 0, 0);
    aV1 = __builtin_amdgcn_mfma_f32_16x16x32_bf16(a, bv1, aV1, 0, 0, 0);
  }
  if (half == 1) {
    *(f32x4*)&comb[grp][lane][0] = aK0;
    *(f32x4*)&comb[grp][lane][4] = aK1;
    *(f32x4*)&comb[grp][lane][8] = aV0;
    *(f32x4*)&comb[grp][lane][12] = aV1;
  }
  __syncthreads();
  if (half == 0) {
    aK0 += *(const f32x4*)&comb[grp][lane][0];
    aK1 += *(const f32x4*)&comb[grp][lane][4];
    aV0 += *(const f32x4*)&comb[grp][lane][8];
    aV1 += *(const f32x4*)&comb[grp][lane][12];
    const int orow = blockIdx.x * 32 + grp * 16 + g * 4;
#pragma unroll
    for (int jj = 0; jj < 4; ++jj) {
      const int r = orow + jj;
      Kbf[(size_t)r * 32 + r15] = f2bf(aK0[jj]);
      Kbf[(size_t)r * 32 + 16 + r15] = f2bf(aK1[jj]);
      const int bb = r >> 10, s = r & 1023;
      Vt[((size_t)bb * 32 + r15) * kS + s] = f2bf(aV0[jj]);
      Vt[((size_t)bb * 32 + 16 + r15) * kS + s] = f2bf(aV1[jj]);
    }
  }
}

// ---------------------------------------------------------------------------
// Fused attention, S-split wave pairs: 256 threads = 4 waves = 2 q-groups
// (16 rows) x 2 s-halves (512 cols). 3 passes (sum/min/diff+PV) with small
// pairwise LDS combines. K read from L2 (no LDS stage). grid = 1024 blocks
// = 4 blocks/CU = 4 waves/SIMD.
// ---------------------------------------------------------------------------
__global__ __launch_bounds__(256, 4) void attn_kernel(
    const float* __restrict__ query, const float* __restrict__ Wq,
    const unsigned short* __restrict__ Kbf,
    const unsigned short* __restrict__ Vt, const void* __restrict__ qmask,
    const void* __restrict__ kmask, const float* __restrict__ lq1,
    const float* __restrict__ lk1, const float* __restrict__ lq2,
    const float* __restrict__ lk2, const float* __restrict__ rmsw,
    const float* __restrict__ Wo, const int* __restrict__ mflag,
    float* __restrict__ out, float* __restrict__ diff) {
  __shared__ __align__(16) float ubuf[2048];  // sWq[1024]+sQi[1024] | nxlds
  __shared__ __align__(16) unsigned short qlds[32][40];
  __shared__ unsigned kmp_lds[256];
  __shared__ float sWo[32][32];
  __shared__ float redA[4][2][16];
  __shared__ float redB[4][16];
  __shared__ float pvred[4][16][33];
  __shared__ float srw[32];
  __shared__ int qmS[32];
  __shared__ float slam;

  float* const sWq = ubuf;
  float* const sQi = ubuf + 1024;
  float* const nxlds = ubuf;  // overlays after qproj

  const int t = threadIdx.x;
  const int lane = t & 63;
  const int w = t >> 6;        // 0..3
  const int group = w >> 1;    // q-group (16 rows)
  const int shalf = w & 1;     // s-half (512 cols)
  const int r15 = lane & 15;
  const int g = lane >> 4;
  const int b = blockIdx.x >> 7;
  const int rowbase = b * kL + (blockIdx.x & 127) * 32;
  const int kvb = b * kS;
  const int fmt = *mflag;

  // ---- stage ----
  {
    *(f32x4*)(sWq + 4 * t) = *(const f32x4*)(Wq + 4 * t);
    *(f32x4*)(&sWo[0][0] + 4 * t) = *(const f32x4*)(Wo + 4 * t);
    const long base = (long)kvb + 4 * t;
    const unsigned m0 = load_mask(kmask, base + 0, fmt) ? 1u : 0u;
    const unsigned m1 = load_mask(kmask, base + 1, fmt) ? 1u : 0u;
    const unsigned m2 = load_mask(kmask, base + 2, fmt) ? 1u : 0u;
    const unsigned m3 = load_mask(kmask, base + 3, fmt) ? 1u : 0u;
    kmp_lds[t] = m0 | (m1 << 8) | (m2 << 16) | (m3 << 24);
    *(f32x4*)(sQi + 4 * t) =
        *(const f32x4*)(query + (size_t)rowbase * 32 + 4 * t);
  }
  if (t < 32) {
    qmS[t] = load_mask(qmask, (long)rowbase + t, fmt);
    srw[t] = rmsw[t];
  }
  if (t == 0) {
    float a = 0.f, c2 = 0.f;
#pragma unroll
    for (int i = 0; i < 16; ++i) {
      a += lq1[i] * lk1[i];
      c2 += lq2[i] * lk2[i];
    }
    slam = expf(a) - expf(c2) + kLamInit;
  }
  __syncthreads();

  // ---- fused Q projection: qlds[q][e] = bf16(dot * scale), 32 rows ----
#pragma unroll
  for (int p = 0; p < 4; ++p) {
    const int idx = t + 256 * p;
    const int row = idx >> 5, col = idx & 31;
    float a = 0.f;
#pragma unroll
    for (int k = 0; k < 32; ++k) a += sQi[row * 32 + k] * sWq[k * 32 + col];
    qlds[row][col] = f2bf(a * kQScale);
  }
  __syncthreads();

  const short8v z8 = {0, 0, 0, 0, 0, 0, 0, 0};
  const f32x4 zf = {0.f, 0.f, 0.f, 0.f};
  const float lam = slam;
  const int qm = qmS[group * 16 + r15];
  const int wrow = rowbase + group * 16;
  const int sbase = shalf * 512;

  short8v qa0 = z8, qa1 = z8;
  if (lane < 32) {
    qa0 = *(const short8v*)&qlds[group * 16 + r15][g * 8];
    qa1 = *(const short8v*)&qlds[group * 16 + r15][16 + g * 8];
  }

  // ---- PASS A: partial sums over this wave's 512 s ----
  f32x4 s0v = zf, s1v = zf;
#pragma unroll
  for (int sl = 0; sl < 4; ++sl) {
#pragma unroll
    for (int c = 0; c < 8; ++c) {
      const int srow = sbase + sl * 128 + c * 16 + r15;
      short8v kb0 = z8, kb1 = z8;
      if (lane < 32) {
        const unsigned short* kr = &Kbf[((size_t)(kvb + srow)) * 32];
        kb0 = *(const short8v*)&kr[g * 8];
        kb1 = *(const short8v*)&kr[16 + g * 8];
      }
      const f32x4 a0 =
          __builtin_amdgcn_mfma_f32_16x16x32_bf16(kb0, qa0, zf, 0, 0, 0);
      const f32x4 a1 =
          __builtin_amdgcn_mfma_f32_16x16x32_bf16(kb1, qa1, zf, 0, 0, 0);
      const unsigned km = kmp_lds[shalf * 128 + sl * 32 + c * 4 + g];
#pragma unroll
      for (int jj = 0; jj < 4; ++jj) {
        const int mbit = (km >> (8 * jj)) & 1u;
        s0v[jj] += mbit ? fast_exp2(a0[jj] - kShift) : 0.f;
        s1v[jj] += mbit ? fast_exp2(a1[jj] - kShift) : 0.f;
      }
    }
  }
  float s0 = (s0v[0] + s0v[1]) + (s0v[2] + s0v[3]);
  float s1 = (s1v[0] + s1v[1]) + (s1v[2] + s1v[3]);
  s0 += __shfl_xor(s0, 16);
  s0 += __shfl_xor(s0, 32);
  s1 += __shfl_xor(s1, 16);
  s1 += __shfl_xor(s1, 32);
  if (lane < 16) {
    redA[w][0][lane] = s0;
    redA[w][1][lane] = s1;
  }
  __syncthreads();
  const float s0t = redA[group * 2][0][r15] + redA[group * 2 + 1][0][r15];
  const float s1t = redA[group * 2][1][r15] + redA[group * 2 + 1][1][r15];
  const float f0 = 1.f / (s0t + 1e-37f);
  const float nf1 = -lam / (s1t + 1e-37f);

  // ---- PASS B: partial row-min of d ----
  f32x4 dmn = {3.0e38f, 3.0e38f, 3.0e38f, 3.0e38f};
#pragma unroll
  for (int sl = 0; sl < 4; ++sl) {
#pragma unroll
    for (int c = 0; c < 8; ++c) {
      const int srow = sbase + sl * 128 + c * 16 + r15;
      short8v kb0 = z8, kb1 = z8;
      if (lane < 32) {
        const unsigned short* kr = &Kbf[((size_t)(kvb + srow)) * 32];
        kb0 = *(const short8v*)&kr[g * 8];
        kb1 = *(const short8v*)&kr[16 + g * 8];
      }
      const f32x4 a0 =
          __builtin_amdgcn_mfma_f32_16x16x32_bf16(kb0, qa0, zf, 0, 0, 0);
      const f32x4 a1 =
          __builtin_amdgcn_mfma_f32_16x16x32_bf16(kb1, qa1, zf, 0, 0, 0);
      const unsigned km = kmp_lds[shalf * 128 + sl * 32 + c * 4 + g];
#pragma unroll
      for (int jj = 0; jj < 4; ++jj) {
        const int mbit = (km >> (8 * jj)) & 1u;
        const float e0 = mbit ? fast_exp2(a0[jj] - kShift) : 0.f;
        const float e1 = mbit ? fast_exp2(a1[jj] - kShift) : 0.f;
        dmn[jj] = fminf(dmn[jj], fmaf(e0, f0, nf1 * e1));
      }
    }
  }
  float dm = fminf(fminf(dmn[0], dmn[1]), fminf(dmn[2], dmn[3]));
  dm = fminf(dm, __shfl_xor(dm, 16));
  dm = fminf(dm, __shfl_xor(dm, 32));
  if (lane < 16) redB[w][lane] = dm;
  __syncthreads();
  const float rmin = fminf(redB[group * 2][r15], redB[group * 2 + 1][r15]);
  const float rme = rmin - 1e-5f;

  // ---- PASS C: diff stores + PV over this wave's 512 s ----
  f32x4 pv0 = zf, pv1 = zf;
  const int sl0 = ((g & 1) << 5) + r15;
  const int sl1 = sl0 + 16;
  const bool hi = (g >> 1) != 0;
#pragma unroll
  for (int sl = 0; sl < 4; ++sl) {
    short8v vt0[4], vt1[4];
#pragma unroll
    for (int kc = 0; kc < 4; ++kc) {
      const int soff = sbase + sl * 128 + kc * 32 + g * 8;
      vt0[kc] = *(const short8v*)&Vt[((size_t)(b * 32 + r15)) * kS + soff];
      vt1[kc] = *(const short8v*)&Vt[((size_t)(b * 32 + 16 + r15)) * kS + soff];
    }
    unsigned pkx[8], pky[8];
#pragma unroll
    for (int c = 0; c < 8; ++c) {
      const int srow = sbase + sl * 128 + c * 16 + r15;
      short8v kb0 = z8, kb1 = z8;
      if (lane < 32) {
        const unsigned short* kr = &Kbf[((size_t)(kvb + srow)) * 32];
        kb0 = *(const short8v*)&kr[g * 8];
        kb1 = *(const short8v*)&kr[16 + g * 8];
      }
      const f32x4 a0 =
          __builtin_amdgcn_mfma_f32_16x16x32_bf16(kb0, qa0, zf, 0, 0, 0);
      const f32x4 a1 =
          __builtin_amdgcn_mfma_f32_16x16x32_bf16(kb1, qa1, zf, 0, 0, 0);
      const unsigned km = kmp_lds[shalf * 128 + sl * 32 + c * 4 + g];
      f32x4 fd;
#pragma unroll
      for (int jj = 0; jj < 4; ++jj) {
        const int mbit = (km >> (8 * jj)) & 1u;
        const float e0 = mbit ? fast_exp2(a0[jj] - kShift) : 0.f;
        const float e1 = mbit ? fast_exp2(a1[jj] - kShift) : 0.f;
        const float d = fmaf(e0, f0, nf1 * e1);
        fd[jj] = (qm && mbit) ? d - rme : 0.f;
      }
      *(f32x4*)&diff[((size_t)(wrow + r15)) * kS + sbase + sl * 128 + c * 16 +
                     g * 4] = fd;
      pkx[c] = (unsigned)f2bf(fd[0]) | ((unsigned)f2bf(fd[1]) << 16);
      pky[c] = (unsigned)f2bf(fd[2]) | ((unsigned)f2bf(fd[3]) << 16);
    }
    // PV gather: broadcast both chunk parities; DEST selects with hi
#pragma unroll
    for (int kc = 0; kc < 4; ++kc) {
      const unsigned x0a = (unsigned)__shfl((int)pkx[2 * kc], sl0);
      const unsigned y0a = (unsigned)__shfl((int)pky[2 * kc], sl0);
      const unsigned x0b = (unsigned)__shfl((int)pkx[2 * kc], sl1);
      const unsigned y0b = (unsigned)__shfl((int)pky[2 * kc], sl1);
      const unsigned x1a = (unsigned)__shfl((int)pkx[2 * kc + 1], sl0);
      const unsigned y1a = (unsigned)__shfl((int)pky[2 * kc + 1], sl0);
      const unsigned x1b = (unsigned)__shfl((int)pkx[2 * kc + 1], sl1);
      const unsigned y1b = (unsigned)__shfl((int)pky[2 * kc + 1], sl1);
      uint4v avw;
      avw.x = hi ? x1a : x0a;
      avw.y = hi ? y1a : y0a;
      avw.z = hi ? x1b : x0b;
      avw.w = hi ? y1b : y0b;
      const short8v av = *(const short8v*)&avw;
      pv0 = __builtin_amdgcn_mfma_f32_16x16x32_bf16(av, vt0[kc], pv0, 0, 0, 0);
      pv1 = __builtin_amdgcn_mfma_f32_16x16x32_bf16(av, vt1[kc], pv1, 0, 0, 0);
    }
  }
#pragma unroll
  for (int jj = 0; jj < 4; ++jj) {
    pvred[w][g * 4 + jj][r15] = pv0[jj];
    pvred[w][g * 4 + jj][16 + r15] = pv1[jj];
  }
  __syncthreads();

  // ---- epilogue: shalf-0 wave per group combines + RMSNorm + @Wo ----
  if (shalf == 0) {
    f32x4 pv0c, pv1c;
#pragma unroll
    for (int jj = 0; jj < 4; ++jj) {
      pv0c[jj] = pvred[w][g * 4 + jj][r15] + pvred[w + 1][g * 4 + jj][r15];
      pv1c[jj] =
          pvred[w][g * 4 + jj][16 + r15] + pvred[w + 1][g * 4 + jj][16 + r15];
    }
    float* const nxw = nxlds + group * (16 * 36);
#pragma unroll
    for (int jj = 0; jj < 4; ++jj) {
      float ss = pv0c[jj] * pv0c[jj] + pv1c[jj] * pv1c[jj];
      ss += __shfl_xor(ss, 1);
      ss += __shfl_xor(ss, 2);
      ss += __shfl_xor(ss, 4);
      ss += __shfl_xor(ss, 8);
      const float rms = 1.0f / sqrtf(ss * (1.f / 32.f) + 1e-5f);
      nxw[(g * 4 + jj) * 36 + r15] = pv0c[jj] * rms * srw[r15] * kOutScale;
      nxw[(g * 4 + jj) * 36 + 16 + r15] =
          pv1c[jj] * rms * srw[16 + r15] * kOutScale;
    }
    asm volatile("s_waitcnt lgkmcnt(0)" ::: "memory");

    const int q2 = lane >> 2;
    const int cg = (lane & 3) * 8;
    float o[8] = {0.f, 0.f, 0.f, 0.f, 0.f, 0.f, 0.f, 0.f};
#pragma unroll
    for (int e = 0; e < 32; ++e) {
      const float nv = nxw[q2 * 36 + e];
#pragma unroll
      for (int j = 0; j < 8; ++j) o[j] += nv * sWo[e][cg + j];
    }
    f32x4 olo = {o[0], o[1], o[2], o[3]};
    f32x4 ohi = {o[4], o[5], o[6], o[7]};
    *(f32x4*)&out[((size_t)(wrow + q2)) * 32 + cg] = olo;
    *(f32x4*)&out[((size_t)(wrow + q2)) * 32 + cg + 4] = ohi;
  }
}

}  // namespace

extern "C" void kernel_launch(void* const* d_in, const int* in_sizes, int n_in,
                              void* d_out, int out_size, void* d_ws,
                              size_t ws_size, hipStream_t stream) {
  const float* query = (const float*)d_in[0];
  const float* key = (const float*)d_in[1];
  const void* qmask = d_in[2];
  const void* kmask = d_in[3];
  const float* Wq = (const float*)d_in[4];
  const float* Wk = (const float*)d_in[5];
  const float* Wv = (const float*)d_in[6];
  const float* Wo = (const float*)d_in[7];
  const float* lq1 = (const float*)d_in[8];
  const float* lk1 = (const float*)d_in[9];
  const float* lq2 = (const float*)d_in[10];
  const float* lk2 = (const float*)d_in[11];
  const float* rmsw = (const float*)d_in[12];

  unsigned short* Kbf = (unsigned short*)d_ws;            // [B*S,32]
  unsigned short* Vt = Kbf + (size_t)kB * kS * 32;        // [B,32,S]
  unsigned short* WkT = Vt + (size_t)kB * kS * 32;        // [32,768]
  unsigned short* WvT = WkT + (size_t)32 * 768;           // [32,768]
  int* mflag = (int*)(WvT + (size_t)32 * 768);

  float* outp = (float*)d_out;
  float* diffp = outp + (size_t)kB * kL * 32;

  prep_kernel<<<dim3(193), dim3(256), 0, stream>>>(
      Wk, Wv, (const unsigned char*)qmask, WkT, WvT, mflag);
  proj_kv_kernel<<<dim3(kB * kS / 32), dim3(256), 0, stream>>>(key, WkT, WvT,
                                                               Kbf, Vt);
  attn_kernel<<<dim3(kB * (kL / 32)), dim3(256), 0, stream>>>(
      query, Wq, Kbf, Vt, qmask, kmask, lq1, lk1, lq2, lk2, rmsw, Wo, mflag,
      outp, diffp);
}

// Round 19
// 380.743 us; speedup vs baseline: 1.1560x; 1.0302x over previous
//
#include <hip/hip_runtime.h>

namespace {

typedef __attribute__((ext_vector_type(8))) short short8v;
typedef __attribute__((ext_vector_type(4))) float f32x4;
typedef __attribute__((ext_vector_type(4))) unsigned int uint4v;

constexpr int kB = 8;
constexpr int kS = 1024;
constexpr int kSUB = 768;
constexpr int kL = 4096;                                   // P*G
constexpr float kQScale = 0.25f * 1.44269504088896340736f; // SCALING*log2(e)
constexpr float kLamInit = 0.2f;
constexpr float kOutScale = 0.8f;

// LDS-only barrier: global stores stay in flight across it.
#define BAR_LGKM() asm volatile("s_waitcnt lgkmcnt(0)\ns_barrier" ::: "memory")

__device__ __forceinline__ unsigned short f2bf(float x) {
  unsigned u = __float_as_uint(x);
  return (unsigned short)((u + 0x7FFFu + ((u >> 16) & 1u)) >> 16);
}

__device__ __forceinline__ float fast_exp2(float x) {
#if __has_builtin(__builtin_amdgcn_exp2f)
  return __builtin_amdgcn_exp2f(x);
#else
  return exp2f(x);
#endif
}

__device__ __forceinline__ int load_mask(const void* p, long i, int fmt) {
  if (fmt == 1) return (int)((const unsigned char*)p)[i];
  if (fmt == 2) return (int)(((const int*)p)[2 * i] != 0);
  return ((const int*)p)[i];
}

// ---------------------------------------------------------------------------
// prep: blocks 0..191 transpose Wk/Wv to bf16 [c][k]; block 192 detects mask
// layout (0=int32,1=u8,2=int64).
// ---------------------------------------------------------------------------
__global__ __launch_bounds__(256) void prep_kernel(
    const float* __restrict__ Wk, const float* __restrict__ Wv,
    const unsigned char* __restrict__ qm, unsigned short* __restrict__ WkT,
    unsigned short* __restrict__ WvT, int* __restrict__ flag) {
  if (blockIdx.x < 192) {
    int idx = blockIdx.x * 256 + threadIdx.x;
    if (idx < 24576) {
      const int k = idx >> 5, c = idx & 31;
      WkT[c * 768 + k] = f2bf(Wk[idx]);
    } else {
      idx -= 24576;
      const int k = idx >> 5, c = idx & 31;
      WvT[c * 768 + k] = f2bf(Wv[idx]);
    }
  } else {
    __shared__ int any14, any47;
    if (threadIdx.x == 0) { any14 = 0; any47 = 0; }
    __syncthreads();
    int l14 = 0, l47 = 0;
    for (int i = threadIdx.x; i < 16384; i += 256) {
      const unsigned char v = qm[i];
      if (v && (i & 3)) l14 = 1;
      if (v && ((i & 7) >= 4)) l47 = 1;
    }
    if (l14) atomicOr(&any14, 1);
    if (l47) atomicOr(&any47, 1);
    __syncthreads();
    if (threadIdx.x == 0) *flag = any14 ? 1 : (any47 ? 0 : 2);
  }
}

// ---------------------------------------------------------------------------
// K/V projection, split-K: 32 rows/block, 256 threads (4 waves).
// ---------------------------------------------------------------------------
__global__ __launch_bounds__(256) void proj_kv_kernel(
    const float* __restrict__ key, const unsigned short* __restrict__ WkT,
    const unsigned short* __restrict__ WvT, unsigned short* __restrict__ Kbf,
    unsigned short* __restrict__ Vt) {
  __shared__ float comb[2][64][20];
  const int t = threadIdx.x;
  const int wv = t >> 6, lane = t & 63;
  const int r15 = lane & 15, g = lane >> 4;
  const int grp = wv >> 1;
  const int half = wv & 1;
  const int row = blockIdx.x * 32 + grp * 16 + r15;
  const int kbase = half * 384;
  const float* kp = &key[(size_t)row * kSUB + kbase];
  const f32x4 zf = {0.f, 0.f, 0.f, 0.f};
  f32x4 aK0 = zf, aK1 = zf, aV0 = zf, aV1 = zf;
#pragma unroll 4
  for (int ks = 0; ks < 384; ks += 32) {
    const f32x4 lo = *(const f32x4*)&kp[ks + g * 8];
    const f32x4 hi = *(const f32x4*)&kp[ks + g * 8 + 4];
    short8v a;
#pragma unroll
    for (int j = 0; j < 4; ++j) {
      a[j] = (short)f2bf(lo[j]);
      a[4 + j] = (short)f2bf(hi[j]);
    }
    const int ko = kbase + ks + g * 8;
    const short8v bk0 = *(const short8v*)&WkT[(size_t)r15 * 768 + ko];
    const short8v bk1 = *(const short8v*)&WkT[(size_t)(16 + r15) * 768 + ko];
    const short8v bv0 = *(const short8v*)&WvT[(size_t)r15 * 768 + ko];
    const short8v bv1 = *(const short8v*)&WvT[(size_t)(16 + r15) * 768 + ko];
    aK0 = __builtin_amdgcn_mfma_f32_16x16x32_bf16(a, bk0, aK0, 0, 0, 0);
    aK1 = __builtin_amdgcn_mfma_f32_16x16x32_bf16(a, bk1, aK1, 0, 0, 0);
    aV0 = __builtin_amdgcn_mfma_f32_16x16x32_bf16(a, bv0, aV0, 0, 0, 0);
    aV1 = __builtin_amdgcn_mfma_f32_16x16x32_bf16(a, bv1, aV1, 0, 0, 0);
  }
  if (half == 1) {
    *(f32x4*)&comb[grp][lane][0] = aK0;
    *(f32x4*)&comb[grp][lane][4] = aK1;
    *(f32x4*)&comb[grp][lane][8] = aV0;
    *(f32x4*)&comb[grp][lane][12] = aV1;
  }
  __syncthreads();
  if (half == 0) {
    aK0 += *(const f32x4*)&comb[grp][lane][0];
    aK1 += *(const f32x4*)&comb[grp][lane][4];
    aV0 += *(const f32x4*)&comb[grp][lane][8];
    aV1 += *(const f32x4*)&comb[grp][lane][12];
    const int orow = blockIdx.x * 32 + grp * 16 + g * 4;
#pragma unroll
    for (int jj = 0; jj < 4; ++jj) {
      const int r = orow + jj;
      Kbf[(size_t)r * 32 + r15] = f2bf(aK0[jj]);
      Kbf[(size_t)r * 32 + 16 + r15] = f2bf(aK1[jj]);
      const int bb = r >> 10, s = r & 1023;
      Vt[((size_t)bb * 32 + r15) * kS + s] = f2bf(aV0[jj]);
      Vt[((size_t)bb * 32 + 16 + r15) * kS + s] = f2bf(aV1[jj]);
    }
  }
}

// ---------------------------------------------------------------------------
// Fused attention: 1024 threads = 16 waves = 8 q-groups (16 rows) x 2
// s-halves (512 cols); 128 q-rows/block, 256 blocks = 1/CU, 4 waves/SIMD.
// K staged in padded [1024][40] LDS (80KB, R15-verified, 2-way conflicts
// only). 3 block-wide barriers total (sum/min/PV combine).
// ---------------------------------------------------------------------------
__global__ __launch_bounds__(1024, 4) void attn_kernel(
    const float* __restrict__ query, const float* __restrict__ Wq,
    const unsigned short* __restrict__ Kbf,
    const unsigned short* __restrict__ Vt, const void* __restrict__ qmask,
    const void* __restrict__ kmask, const float* __restrict__ lq1,
    const float* __restrict__ lk1, const float* __restrict__ lq2,
    const float* __restrict__ lk2, const float* __restrict__ rmsw,
    const float* __restrict__ Wo, const int* __restrict__ mflag,
    float* __restrict__ out, float* __restrict__ diff) {
  __shared__ __align__(16) unsigned short kfl[1024 * 40];  // 80KB padded
  __shared__ __align__(16) float ubuf[5120];  // {sWq 4K + sQi 16K} | pvred/nx
  __shared__ __align__(16) unsigned short qlds[128][40];
  __shared__ unsigned kmp_lds[256];
  __shared__ float sWo[32][32];
  __shared__ float redA[16][2][16];
  __shared__ float redB[16][16];
  __shared__ float srw[32];
  __shared__ int qmS[128];
  __shared__ float slam;

  float* const sWq = ubuf;
  float* const sQi = ubuf + 1024;
  float* const pvred = ubuf;  // [8][16][34] overlays after qproj

  const int t = threadIdx.x;
  const int lane = t & 63;
  const int w = t >> 6;        // 0..15
  const int group = w >> 1;    // 0..7 (16 q-rows each)
  const int shalf = w & 1;     // s-half (512 cols)
  const int r15 = lane & 15;
  const int g = lane >> 4;
  const int b = blockIdx.x >> 5;
  const int rowbase = b * kL + (blockIdx.x & 31) * 128;
  const int kvb = b * kS;
  const int fmt = *mflag;

  // ---- stage ----
  if (t < 256) {
    *(f32x4*)(sWq + 4 * t) = *(const f32x4*)(Wq + 4 * t);
    *(f32x4*)(&sWo[0][0] + 4 * t) = *(const f32x4*)(Wo + 4 * t);
    const long base = (long)kvb + 4 * t;
    const unsigned m0 = load_mask(kmask, base + 0, fmt) ? 1u : 0u;
    const unsigned m1 = load_mask(kmask, base + 1, fmt) ? 1u : 0u;
    const unsigned m2 = load_mask(kmask, base + 2, fmt) ? 1u : 0u;
    const unsigned m3 = load_mask(kmask, base + 3, fmt) ? 1u : 0u;
    kmp_lds[t] = m0 | (m1 << 8) | (m2 << 16) | (m3 << 24);
  }
  *(f32x4*)(sQi + 4 * t) = *(const f32x4*)(query + (size_t)rowbase * 32 + 4 * t);
  {
    // stage K row t into padded [1024][40] layout (R15-verified)
    const short8v* src = (const short8v*)&Kbf[((size_t)(kvb + t)) * 32];
    *(short8v*)&kfl[t * 40 + 0] = src[0];
    *(short8v*)&kfl[t * 40 + 8] = src[1];
    *(short8v*)&kfl[t * 40 + 16] = src[2];
    *(short8v*)&kfl[t * 40 + 24] = src[3];
  }
  if (t < 128) qmS[t] = load_mask(qmask, (long)rowbase + t, fmt);
  if (t < 32) srw[t] = rmsw[t];
  if (t == 0) {
    float a = 0.f, c2 = 0.f;
#pragma unroll
    for (int i = 0; i < 16; ++i) {
      a += lq1[i] * lk1[i];
      c2 += lq2[i] * lk2[i];
    }
    slam = expf(a) - expf(c2) + kLamInit;
  }
  __syncthreads();

  // ---- fused Q projection: qlds[q][e] = bf16(dot * scale), 128 rows ----
#pragma unroll
  for (int p = 0; p < 4; ++p) {
    const int idx = t + 1024 * p;
    const int row = idx >> 5, col = idx & 31;
    float a = 0.f;
#pragma unroll
    for (int k = 0; k < 32; ++k) a += sQi[row * 32 + k] * sWq[k * 32 + col];
    qlds[row][col] = f2bf(a * kQScale);
  }
  __syncthreads();

  const short8v z8 = {0, 0, 0, 0, 0, 0, 0, 0};
  const f32x4 zf = {0.f, 0.f, 0.f, 0.f};
  const float lam = slam;
  const int qm = qmS[group * 16 + r15];
  const int wrow = rowbase + group * 16;
  const int sbase = shalf * 512;

  short8v qa0 = z8, qa1 = z8;
  if (lane < 32) {
    qa0 = *(const short8v*)&qlds[group * 16 + r15][g * 8];
    qa1 = *(const short8v*)&qlds[group * 16 + r15][16 + g * 8];
  }

  // ---- PASS A: partial sums of exp2(score) over this wave's 512 s ----
  f32x4 s0v = zf, s1v = zf;
#pragma unroll
  for (int sl = 0; sl < 4; ++sl) {
#pragma unroll
    for (int c = 0; c < 8; ++c) {
      const int srow = sbase + sl * 128 + c * 16 + r15;
      short8v kb0 = z8, kb1 = z8;
      if (lane < 32) {
        kb0 = *(const short8v*)&kfl[srow * 40 + g * 8];
        kb1 = *(const short8v*)&kfl[srow * 40 + 16 + g * 8];
      }
      const f32x4 a0 =
          __builtin_amdgcn_mfma_f32_16x16x32_bf16(kb0, qa0, zf, 0, 0, 0);
      const f32x4 a1 =
          __builtin_amdgcn_mfma_f32_16x16x32_bf16(kb1, qa1, zf, 0, 0, 0);
      const unsigned km = kmp_lds[shalf * 128 + sl * 32 + c * 4 + g];
#pragma unroll
      for (int jj = 0; jj < 4; ++jj) {
        const int mbit = (km >> (8 * jj)) & 1u;
        s0v[jj] += mbit ? fast_exp2(a0[jj]) : 0.f;
        s1v[jj] += mbit ? fast_exp2(a1[jj]) : 0.f;
      }
    }
  }
  float s0 = (s0v[0] + s0v[1]) + (s0v[2] + s0v[3]);
  float s1 = (s1v[0] + s1v[1]) + (s1v[2] + s1v[3]);
  s0 += __shfl_xor(s0, 16);
  s0 += __shfl_xor(s0, 32);
  s1 += __shfl_xor(s1, 16);
  s1 += __shfl_xor(s1, 32);
  if (lane < 16) {
    redA[w][0][lane] = s0;
    redA[w][1][lane] = s1;
  }
  BAR_LGKM();  // B1
  const float s0t = redA[group * 2][0][r15] + redA[group * 2 + 1][0][r15];
  const float s1t = redA[group * 2][1][r15] + redA[group * 2 + 1][1][r15];
  const float f0 = 1.f / (s0t + 1e-37f);
  const float nf1 = -lam / (s1t + 1e-37f);

  // ---- PASS B: partial row-min of d ----
  f32x4 dmn = {3.0e38f, 3.0e38f, 3.0e38f, 3.0e38f};
#pragma unroll
  for (int sl = 0; sl < 4; ++sl) {
#pragma unroll
    for (int c = 0; c < 8; ++c) {
      const int srow = sbase + sl * 128 + c * 16 + r15;
      short8v kb0 = z8, kb1 = z8;
      if (lane < 32) {
        kb0 = *(const short8v*)&kfl[srow * 40 + g * 8];
        kb1 = *(const short8v*)&kfl[srow * 40 + 16 + g * 8];
      }
      const f32x4 a0 =
          __builtin_amdgcn_mfma_f32_16x16x32_bf16(kb0, qa0, zf, 0, 0, 0);
      const f32x4 a1 =
          __builtin_amdgcn_mfma_f32_16x16x32_bf16(kb1, qa1, zf, 0, 0, 0);
      const unsigned km = kmp_lds[shalf * 128 + sl * 32 + c * 4 + g];
#pragma unroll
      for (int jj = 0; jj < 4; ++jj) {
        const int mbit = (km >> (8 * jj)) & 1u;
        const float e0 = mbit ? fast_exp2(a0[jj]) : 0.f;
        const float e1 = mbit ? fast_exp2(a1[jj]) : 0.f;
        dmn[jj] = fminf(dmn[jj], fmaf(e0, f0, nf1 * e1));
      }
    }
  }
  float dm = fminf(fminf(dmn[0], dmn[1]), fminf(dmn[2], dmn[3]));
  dm = fminf(dm, __shfl_xor(dm, 16));
  dm = fminf(dm, __shfl_xor(dm, 32));
  if (lane < 16) redB[w][lane] = dm;
  BAR_LGKM();  // B2
  const float rmin = fminf(redB[group * 2][r15], redB[group * 2 + 1][r15]);
  const float rme = rmin - 1e-5f;

  // ---- PASS C: diff stores + partial PV over this wave's 512 s ----
  f32x4 pv0 = zf, pv1 = zf;
  const int sl0 = ((g & 1) << 5) + r15;
  const int sl1 = sl0 + 16;
  const bool hi = (g >> 1) != 0;
#pragma unroll
  for (int sl = 0; sl < 4; ++sl) {
    short8v vt0[4], vt1[4];
#pragma unroll
    for (int kc = 0; kc < 4; ++kc) {
      const int soff = sbase + sl * 128 + kc * 32 + g * 8;
      vt0[kc] = *(const short8v*)&Vt[((size_t)(b * 32 + r15)) * kS + soff];
      vt1[kc] = *(const short8v*)&Vt[((size_t)(b * 32 + 16 + r15)) * kS + soff];
    }
    unsigned pkx[8], pky[8];
#pragma unroll
    for (int c = 0; c < 8; ++c) {
      const int srow = sbase + sl * 128 + c * 16 + r15;
      short8v kb0 = z8, kb1 = z8;
      if (lane < 32) {
        kb0 = *(const short8v*)&kfl[srow * 40 + g * 8];
        kb1 = *(const short8v*)&kfl[srow * 40 + 16 + g * 8];
      }
      const f32x4 a0 =
          __builtin_amdgcn_mfma_f32_16x16x32_bf16(kb0, qa0, zf, 0, 0, 0);
      const f32x4 a1 =
          __builtin_amdgcn_mfma_f32_16x16x32_bf16(kb1, qa1, zf, 0, 0, 0);
      const unsigned km = kmp_lds[shalf * 128 + sl * 32 + c * 4 + g];
      f32x4 fd;
#pragma unroll
      for (int jj = 0; jj < 4; ++jj) {
        const int mbit = (km >> (8 * jj)) & 1u;
        const float e0 = mbit ? fast_exp2(a0[jj]) : 0.f;
        const float e1 = mbit ? fast_exp2(a1[jj]) : 0.f;
        const float d = fmaf(e0, f0, nf1 * e1);
        fd[jj] = (qm && mbit) ? d - rme : 0.f;
      }
      *(f32x4*)&diff[((size_t)(wrow + r15)) * kS + sbase + sl * 128 + c * 16 +
                     g * 4] = fd;
      pkx[c] = (unsigned)f2bf(fd[0]) | ((unsigned)f2bf(fd[1]) << 16);
      pky[c] = (unsigned)f2bf(fd[2]) | ((unsigned)f2bf(fd[3]) << 16);
    }
    // PV gather: broadcast both chunk parities; DEST selects with hi
#pragma unroll
    for (int kc = 0; kc < 4; ++kc) {
      const unsigned x0a = (unsigned)__shfl((int)pkx[2 * kc], sl0);
      const unsigned y0a = (unsigned)__shfl((int)pky[2 * kc], sl0);
      const unsigned x0b = (unsigned)__shfl((int)pkx[2 * kc], sl1);
      const unsigned y0b = (unsigned)__shfl((int)pky[2 * kc], sl1);
      const unsigned x1a = (unsigned)__shfl((int)pkx[2 * kc + 1], sl0);
      const unsigned y1a = (unsigned)__shfl((int)pky[2 * kc + 1], sl0);
      const unsigned x1b = (unsigned)__shfl((int)pkx[2 * kc + 1], sl1);
      const unsigned y1b = (unsigned)__shfl((int)pky[2 * kc + 1], sl1);
      uint4v avw;
      avw.x = hi ? x1a : x0a;
      avw.y = hi ? y1a : y0a;
      avw.z = hi ? x1b : x0b;
      avw.w = hi ? y1b : y0b;
      const short8v av = *(const short8v*)&avw;
      pv0 = __builtin_amdgcn_mfma_f32_16x16x32_bf16(av, vt0[kc], pv0, 0, 0, 0);
      pv1 = __builtin_amdgcn_mfma_f32_16x16x32_bf16(av, vt1[kc], pv1, 0, 0, 0);
    }
  }
  // shalf==1 waves publish partials; shalf==0 keep theirs in regs
  if (shalf == 1) {
#pragma unroll
    for (int jj = 0; jj < 4; ++jj) {
      pvred[group * 544 + (g * 4 + jj) * 34 + r15] = pv0[jj];
      pvred[group * 544 + (g * 4 + jj) * 34 + 16 + r15] = pv1[jj];
    }
  }
  BAR_LGKM();  // B3 (diff stores stay in flight)

  // ---- epilogue: shalf==0 waves combine + RMSNorm + @Wo ----
  if (shalf == 0) {
    f32x4 pv0c, pv1c;
#pragma unroll
    for (int jj = 0; jj < 4; ++jj) {
      pv0c[jj] = pv0[jj] + pvred[group * 544 + (g * 4 + jj) * 34 + r15];
      pv1c[jj] = pv1[jj] + pvred[group * 544 + (g * 4 + jj) * 34 + 16 + r15];
    }
    float* const nxw = pvred + group * 544;  // reuse own-group region
#pragma unroll
    for (int jj = 0; jj < 4; ++jj) {
      float ss = pv0c[jj] * pv0c[jj] + pv1c[jj] * pv1c[jj];
      ss += __shfl_xor(ss, 1);
      ss += __shfl_xor(ss, 2);
      ss += __shfl_xor(ss, 4);
      ss += __shfl_xor(ss, 8);
      const float rms = 1.0f / sqrtf(ss * (1.f / 32.f) + 1e-5f);
      nxw[(g * 4 + jj) * 34 + r15] = pv0c[jj] * rms * srw[r15] * kOutScale;
      nxw[(g * 4 + jj) * 34 + 16 + r15] =
          pv1c[jj] * rms * srw[16 + r15] * kOutScale;
    }
    asm volatile("s_waitcnt lgkmcnt(0)" ::: "memory");

    const int q2 = lane >> 2;
    const int cg = (lane & 3) * 8;
    float o[8] = {0.f, 0.f, 0.f, 0.f, 0.f, 0.f, 0.f, 0.f};
#pragma unroll
    for (int e = 0; e < 32; ++e) {
      const float nv = nxw[q2 * 34 + e];
#pragma unroll
      for (int j = 0; j < 8; ++j) o[j] += nv * sWo[e][cg + j];
    }
    f32x4 olo = {o[0], o[1], o[2], o[3]};
    f32x4 ohi = {o[4], o[5], o[6], o[7]};
    *(f32x4*)&out[((size_t)(wrow + q2)) * 32 + cg] = olo;
    *(f32x4*)&out[((size_t)(wrow + q2)) * 32 + cg + 4] = ohi;
  }
}

}  // namespace

extern "C" void kernel_launch(void* const* d_in, const int* in_sizes, int n_in,
                              void* d_out, int out_size, void* d_ws,
                              size_t ws_size, hipStream_t stream) {
  const float* query = (const float*)d_in[0];
  const float* key = (const float*)d_in[1];
  const void* qmask = d_in[2];
  const void* kmask = d_in[3];
  const float* Wq = (const float*)d_in[4];
  const float* Wk = (const float*)d_in[5];
  const float* Wv = (const float*)d_in[6];
  const float* Wo = (const float*)d_in[7];
  const float* lq1 = (const float*)d_in[8];
  const float* lk1 = (const float*)d_in[9];
  const float* lq2 = (const float*)d_in[10];
  const float* lk2 = (const float*)d_in[11];
  const float* rmsw = (const float*)d_in[12];

  unsigned short* Kbf = (unsigned short*)d_ws;            // [B*S,32]
  unsigned short* Vt = Kbf + (size_t)kB * kS * 32;        // [B,32,S]
  unsigned short* WkT = Vt + (size_t)kB * kS * 32;        // [32,768]
  unsigned short* WvT = WkT + (size_t)32 * 768;           // [32,768]
  int* mflag = (int*)(WvT + (size_t)32 * 768);

  float* outp = (float*)d_out;
  float* diffp = outp + (size_t)kB * kL * 32;

  prep_kernel<<<dim3(193), dim3(256), 0, stream>>>(
      Wk, Wv, (const unsigned char*)qmask, WkT, WvT, mflag);
  proj_kv_kernel<<<dim3(kB * kS / 32), dim3(256), 0, stream>>>(key, WkT, WvT,
                                                               Kbf, Vt);
  attn_kernel<<<dim3(kB * (kL / 128)), dim3(1024), 0, stream>>>(
      query, Wq, Kbf, Vt, qmask, kmask, lq1, lk1, lq2, lk2, rmsw, Wo, mflag,
      outp, diffp);
}

// Round 20
// 99.471 us; speedup vs baseline: 4.4246x; 3.8277x over previous
//
#include <hip/hip_runtime.h>

namespace {

typedef __attribute__((ext_vector_type(8))) short short8v;
typedef __attribute__((ext_vector_type(4))) float f32x4;
typedef __attribute__((ext_vector_type(4))) unsigned int uint4v;

constexpr int kB = 8;
constexpr int kS = 1024;
constexpr int kSUB = 768;
constexpr int kL = 4096;                                   // P*G
constexpr float kQScale = 0.25f * 1.44269504088896340736f; // SCALING*log2(e)
constexpr float kLamInit = 0.2f;
constexpr float kOutScale = 0.8f;

__device__ __forceinline__ unsigned short f2bf(float x) {
  unsigned u = __float_as_uint(x);
  return (unsigned short)((u + 0x7FFFu + ((u >> 16) & 1u)) >> 16);
}

__device__ __forceinline__ float fast_exp2(float x) {
#if __has_builtin(__builtin_amdgcn_exp2f)
  return __builtin_amdgcn_exp2f(x);
#else
  return exp2f(x);
#endif
}

__device__ __forceinline__ int load_mask(const void* p, long i, int fmt) {
  if (fmt == 1) return (int)((const unsigned char*)p)[i];
  if (fmt == 2) return (int)(((const int*)p)[2 * i] != 0);
  return ((const int*)p)[i];
}

// ---------------------------------------------------------------------------
// prep: blocks 0..191 transpose Wk/Wv to bf16 [c][k]; block 192 detects mask
// layout (0=int32,1=u8,2=int64).
// ---------------------------------------------------------------------------
__global__ __launch_bounds__(256) void prep_kernel(
    const float* __restrict__ Wk, const float* __restrict__ Wv,
    const unsigned char* __restrict__ qm, unsigned short* __restrict__ WkT,
    unsigned short* __restrict__ WvT, int* __restrict__ flag) {
  if (blockIdx.x < 192) {
    int idx = blockIdx.x * 256 + threadIdx.x;
    if (idx < 24576) {
      const int k = idx >> 5, c = idx & 31;
      WkT[c * 768 + k] = f2bf(Wk[idx]);
    } else {
      idx -= 24576;
      const int k = idx >> 5, c = idx & 31;
      WvT[c * 768 + k] = f2bf(Wv[idx]);
    }
  } else {
    __shared__ int any14, any47;
    if (threadIdx.x == 0) { any14 = 0; any47 = 0; }
    __syncthreads();
    int l14 = 0, l47 = 0;
    for (int i = threadIdx.x; i < 16384; i += 256) {
      const unsigned char v = qm[i];
      if (v && (i & 3)) l14 = 1;
      if (v && ((i & 7) >= 4)) l47 = 1;
    }
    if (l14) atomicOr(&any14, 1);
    if (l47) atomicOr(&any47, 1);
    __syncthreads();
    if (threadIdx.x == 0) *flag = any14 ? 1 : (any47 ? 0 : 2);
  }
}

// ---------------------------------------------------------------------------
// K/V projection, split-K: 32 rows/block, 256 threads (4 waves).
// ---------------------------------------------------------------------------
__global__ __launch_bounds__(256) void proj_kv_kernel(
    const float* __restrict__ key, const unsigned short* __restrict__ WkT,
    const unsigned short* __restrict__ WvT, unsigned short* __restrict__ Kbf,
    unsigned short* __restrict__ Vt) {
  __shared__ float comb[2][64][20];
  const int t = threadIdx.x;
  const int wv = t >> 6, lane = t & 63;
  const int r15 = lane & 15, g = lane >> 4;
  const int grp = wv >> 1;
  const int half = wv & 1;
  const int row = blockIdx.x * 32 + grp * 16 + r15;
  const int kbase = half * 384;
  const float* kp = &key[(size_t)row * kSUB + kbase];
  const f32x4 zf = {0.f, 0.f, 0.f, 0.f};
  f32x4 aK0 = zf, aK1 = zf, aV0 = zf, aV1 = zf;
#pragma unroll 4
  for (int ks = 0; ks < 384; ks += 32) {
    const f32x4 lo = *(const f32x4*)&kp[ks + g * 8];
    const f32x4 hi = *(const f32x4*)&kp[ks + g * 8 + 4];
    short8v a;
#pragma unroll
    for (int j = 0; j < 4; ++j) {
      a[j] = (short)f2bf(lo[j]);
      a[4 + j] = (short)f2bf(hi[j]);
    }
    const int ko = kbase + ks + g * 8;
    const short8v bk0 = *(const short8v*)&WkT[(size_t)r15 * 768 + ko];
    const short8v bk1 = *(const short8v*)&WkT[(size_t)(16 + r15) * 768 + ko];
    const short8v bv0 = *(const short8v*)&WvT[(size_t)r15 * 768 + ko];
    const short8v bv1 = *(const short8v*)&WvT[(size_t)(16 + r15) * 768 + ko];
    aK0 = __builtin_amdgcn_mfma_f32_16x16x32_bf16(a, bk0, aK0, 0, 0, 0);
    aK1 = __builtin_amdgcn_mfma_f32_16x16x32_bf16(a, bk1, aK1, 0, 0, 0);
    aV0 = __builtin_amdgcn_mfma_f32_16x16x32_bf16(a, bv0, aV0, 0, 0, 0);
    aV1 = __builtin_amdgcn_mfma_f32_16x16x32_bf16(a, bv1, aV1, 0, 0, 0);
  }
  if (half == 1) {
    *(f32x4*)&comb[grp][lane][0] = aK0;
    *(f32x4*)&comb[grp][lane][4] = aK1;
    *(f32x4*)&comb[grp][lane][8] = aV0;
    *(f32x4*)&comb[grp][lane][12] = aV1;
  }
  __syncthreads();
  if (half == 0) {
    aK0 += *(const f32x4*)&comb[grp][lane][0];
    aK1 += *(const f32x4*)&comb[grp][lane][4];
    aV0 += *(const f32x4*)&comb[grp][lane][8];
    aV1 += *(const f32x4*)&comb[grp][lane][12];
    const int orow = blockIdx.x * 32 + grp * 16 + g * 4;
#pragma unroll
    for (int jj = 0; jj < 4; ++jj) {
      const int r = orow + jj;
      Kbf[(size_t)r * 32 + r15] = f2bf(aK0[jj]);
      Kbf[(size_t)r * 32 + 16 + r15] = f2bf(aK1[jj]);
      const int bb = r >> 10, s = r & 1023;
      Vt[((size_t)bb * 32 + r15) * kS + s] = f2bf(aV0[jj]);
      Vt[((size_t)bb * 32 + 16 + r15) * kS + s] = f2bf(aV1[jj]);
    }
  }
}

// ---------------------------------------------------------------------------
// Fused attention, wave-owns-full-row (R15-verified): each of 8 waves owns
// 16 q-rows over the full S=1024, in 3 passes (sum / min / diff+PV). All
// reductions are in-wave shfl; ZERO barriers/atomics/cross-wave traffic in
// the worker loop. K staged once in 80KB dynamic LDS. grid = 256 = 1/CU.
// ---------------------------------------------------------------------------
__global__ __launch_bounds__(512, 2) void attn_kernel(
    const float* __restrict__ query, const float* __restrict__ Wq,
    const unsigned short* __restrict__ Kbf,
    const unsigned short* __restrict__ Vt, const void* __restrict__ qmask,
    const void* __restrict__ kmask, const float* __restrict__ lq1,
    const float* __restrict__ lk1, const float* __restrict__ lq2,
    const float* __restrict__ lk2, const float* __restrict__ rmsw,
    const float* __restrict__ Wo, const int* __restrict__ mflag,
    float* __restrict__ out, float* __restrict__ diff) {
  extern __shared__ __align__(16) unsigned short kfl[];  // [1024][40] 80KB

  __shared__ __align__(16) float ubuf[5120];  // {sWq 1K + sQi 4K} | nxlds
  __shared__ __align__(16) unsigned short qlds[128][40];
  __shared__ unsigned kmp_lds[256];
  __shared__ float sWo[32][32];
  __shared__ float srw[32];
  __shared__ int qmS[128];
  __shared__ float slam;

  float* const sWq = ubuf;
  float* const sQi = ubuf + 1024;
  float* const nxlds = ubuf;  // overlays sWq/sQi after the qproj barrier

  const int t = threadIdx.x;
  const int lane = t & 63;
  const int w = t >> 6;
  const int r15 = lane & 15;
  const int g = lane >> 4;
  const int b = blockIdx.x >> 5;
  const int rowbase = b * kL + (blockIdx.x & 31) * 128;
  const int kvb = b * kS;
  const int fmt = *mflag;

  // ---- stage (once per 128 rows) ----
  if (t < 256) {
    *(f32x4*)(sWq + 4 * t) = *(const f32x4*)(Wq + 4 * t);
    *(f32x4*)(&sWo[0][0] + 4 * t) = *(const f32x4*)(Wo + 4 * t);
    const long base = (long)kvb + 4 * t;
    const unsigned m0 = load_mask(kmask, base + 0, fmt) ? 1u : 0u;
    const unsigned m1 = load_mask(kmask, base + 1, fmt) ? 1u : 0u;
    const unsigned m2 = load_mask(kmask, base + 2, fmt) ? 1u : 0u;
    const unsigned m3 = load_mask(kmask, base + 3, fmt) ? 1u : 0u;
    kmp_lds[t] = m0 | (m1 << 8) | (m2 << 16) | (m3 << 24);
  }
  *(f32x4*)(sQi + 8 * t) = *(const f32x4*)(query + (size_t)rowbase * 32 + 8 * t);
  *(f32x4*)(sQi + 8 * t + 4) =
      *(const f32x4*)(query + (size_t)rowbase * 32 + 8 * t + 4);
#pragma unroll
  for (int p = 0; p < 8; ++p) {
    const int i = t + 512 * p;  // 0..4095: (row, quarter)
    const int row = i >> 2, qtr = i & 3;
    *(short8v*)&kfl[row * 40 + qtr * 8] =
        *(const short8v*)&Kbf[((size_t)(kvb + row)) * 32 + qtr * 8];
  }
  if (t < 128) qmS[t] = load_mask(qmask, (long)rowbase + t, fmt);
  if (t < 32) srw[t] = rmsw[t];
  if (t == 0) {
    float a = 0.f, c2 = 0.f;
#pragma unroll
    for (int i = 0; i < 16; ++i) {
      a += lq1[i] * lk1[i];
      c2 += lq2[i] * lk2[i];
    }
    slam = expf(a) - expf(c2) + kLamInit;
  }
  __syncthreads();

  // ---- fused Q projection: qlds[q][e] = bf16(dot * scale), 128 rows ----
#pragma unroll
  for (int p = 0; p < 8; ++p) {
    const int idx = t + 512 * p;
    const int row = idx >> 5, col = idx & 31;
    float a = 0.f;
#pragma unroll
    for (int k = 0; k < 32; ++k) a += sQi[row * 32 + k] * sWq[k * 32 + col];
    qlds[row][col] = f2bf(a * kQScale);
  }
  __syncthreads();  // last barrier; worker loop below is barrier-free

  const short8v z8 = {0, 0, 0, 0, 0, 0, 0, 0};
  const f32x4 zf = {0.f, 0.f, 0.f, 0.f};
  const float lam = slam;
  const int qm = qmS[w * 16 + r15];
  const int wrow = rowbase + w * 16;  // this wave's first q-row

  short8v qa0 = z8, qa1 = z8;
  if (lane < 32) {
    qa0 = *(const short8v*)&qlds[w * 16 + r15][g * 8];
    qa1 = *(const short8v*)&qlds[w * 16 + r15][16 + g * 8];
  }

  // ---- PASS A: sum of exp2(score) per (q,head), full S (no shift:
  // softmax ratios cancel; |score| << 120 so exp2 cannot overflow) ----
  f32x4 s0v = zf, s1v = zf;
  for (int sl = 0; sl < 8; ++sl) {
#pragma unroll
    for (int c = 0; c < 8; ++c) {
      const int srow = sl * 128 + c * 16 + r15;
      short8v kb0 = z8, kb1 = z8;
      if (lane < 32) {
        kb0 = *(const short8v*)&kfl[srow * 40 + g * 8];
        kb1 = *(const short8v*)&kfl[srow * 40 + 16 + g * 8];
      }
      const f32x4 a0 =
          __builtin_amdgcn_mfma_f32_16x16x32_bf16(kb0, qa0, zf, 0, 0, 0);
      const f32x4 a1 =
          __builtin_amdgcn_mfma_f32_16x16x32_bf16(kb1, qa1, zf, 0, 0, 0);
      const unsigned km = kmp_lds[sl * 32 + c * 4 + g];
#pragma unroll
      for (int jj = 0; jj < 4; ++jj) {
        const int mbit = (km >> (8 * jj)) & 1u;
        s0v[jj] += mbit ? fast_exp2(a0[jj]) : 0.f;
        s1v[jj] += mbit ? fast_exp2(a1[jj]) : 0.f;
      }
    }
  }
  float s0 = (s0v[0] + s0v[1]) + (s0v[2] + s0v[3]);
  float s1 = (s1v[0] + s1v[1]) + (s1v[2] + s1v[3]);
  s0 += __shfl_xor(s0, 16);
  s0 += __shfl_xor(s0, 32);
  s1 += __shfl_xor(s1, 16);
  s1 += __shfl_xor(s1, 32);
  const float f0 = 1.f / (s0 + 1e-37f);
  const float nf1 = -lam / (s1 + 1e-37f);

  // ---- PASS B: row min of d ----
  f32x4 dmn = {3.0e38f, 3.0e38f, 3.0e38f, 3.0e38f};
  for (int sl = 0; sl < 8; ++sl) {
#pragma unroll
    for (int c = 0; c < 8; ++c) {
      const int srow = sl * 128 + c * 16 + r15;
      short8v kb0 = z8, kb1 = z8;
      if (lane < 32) {
        kb0 = *(const short8v*)&kfl[srow * 40 + g * 8];
        kb1 = *(const short8v*)&kfl[srow * 40 + 16 + g * 8];
      }
      const f32x4 a0 =
          __builtin_amdgcn_mfma_f32_16x16x32_bf16(kb0, qa0, zf, 0, 0, 0);
      const f32x4 a1 =
          __builtin_amdgcn_mfma_f32_16x16x32_bf16(kb1, qa1, zf, 0, 0, 0);
      const unsigned km = kmp_lds[sl * 32 + c * 4 + g];
#pragma unroll
      for (int jj = 0; jj < 4; ++jj) {
        const int mbit = (km >> (8 * jj)) & 1u;
        const float e0 = mbit ? fast_exp2(a0[jj]) : 0.f;
        const float e1 = mbit ? fast_exp2(a1[jj]) : 0.f;
        dmn[jj] = fminf(dmn[jj], fmaf(e0, f0, nf1 * e1));
      }
    }
  }
  float dm = fminf(fminf(dmn[0], dmn[1]), fminf(dmn[2], dmn[3]));
  dm = fminf(dm, __shfl_xor(dm, 16));
  dm = fminf(dm, __shfl_xor(dm, 32));
  const float rme = dm - 1e-5f;  // rmin - eps

  // ---- PASS C: diff stores + PV (register-chained MFMA accumulate) ----
  f32x4 pv0 = zf, pv1 = zf;
  const int sl0 = ((g & 1) << 5) + r15;  // PV gather source lanes
  const int sl1 = sl0 + 16;
  const bool hi = (g >> 1) != 0;
  for (int sl = 0; sl < 8; ++sl) {
    short8v vt0[4], vt1[4];
#pragma unroll
    for (int kc = 0; kc < 4; ++kc) {
      const int soff = sl * 128 + kc * 32 + g * 8;
      vt0[kc] = *(const short8v*)&Vt[((size_t)(b * 32 + r15)) * kS + soff];
      vt1[kc] = *(const short8v*)&Vt[((size_t)(b * 32 + 16 + r15)) * kS + soff];
    }
    unsigned pkx[8], pky[8];
#pragma unroll
    for (int c = 0; c < 8; ++c) {
      const int srow = sl * 128 + c * 16 + r15;
      short8v kb0 = z8, kb1 = z8;
      if (lane < 32) {
        kb0 = *(const short8v*)&kfl[srow * 40 + g * 8];
        kb1 = *(const short8v*)&kfl[srow * 40 + 16 + g * 8];
      }
      const f32x4 a0 =
          __builtin_amdgcn_mfma_f32_16x16x32_bf16(kb0, qa0, zf, 0, 0, 0);
      const f32x4 a1 =
          __builtin_amdgcn_mfma_f32_16x16x32_bf16(kb1, qa1, zf, 0, 0, 0);
      const unsigned km = kmp_lds[sl * 32 + c * 4 + g];
      f32x4 fd;
#pragma unroll
      for (int jj = 0; jj < 4; ++jj) {
        const int mbit = (km >> (8 * jj)) & 1u;
        const float e0 = mbit ? fast_exp2(a0[jj]) : 0.f;
        const float e1 = mbit ? fast_exp2(a1[jj]) : 0.f;
        const float d = fmaf(e0, f0, nf1 * e1);
        fd[jj] = (qm && mbit) ? d - rme : 0.f;
      }
      pkx[c] = (unsigned)f2bf(fd[0]) | ((unsigned)f2bf(fd[1]) << 16);
      pky[c] = (unsigned)f2bf(fd[2]) | ((unsigned)f2bf(fd[3]) << 16);
      *(f32x4*)&diff[((size_t)(wrow + r15)) * kS + sl * 128 + c * 16 + g * 4] =
          fd;
    }
    // PV gather: broadcast both chunk parities; DEST selects with hi
#pragma unroll
    for (int kc = 0; kc < 4; ++kc) {
      const unsigned x0a = (unsigned)__shfl((int)pkx[2 * kc], sl0);
      const unsigned y0a = (unsigned)__shfl((int)pky[2 * kc], sl0);
      const unsigned x0b = (unsigned)__shfl((int)pkx[2 * kc], sl1);
      const unsigned y0b = (unsigned)__shfl((int)pky[2 * kc], sl1);
      const unsigned x1a = (unsigned)__shfl((int)pkx[2 * kc + 1], sl0);
      const unsigned y1a = (unsigned)__shfl((int)pky[2 * kc + 1], sl0);
      const unsigned x1b = (unsigned)__shfl((int)pkx[2 * kc + 1], sl1);
      const unsigned y1b = (unsigned)__shfl((int)pky[2 * kc + 1], sl1);
      uint4v avw;
      avw.x = hi ? x1a : x0a;
      avw.y = hi ? y1a : y0a;
      avw.z = hi ? x1b : x0b;
      avw.w = hi ? y1b : y0b;
      const short8v av = *(const short8v*)&avw;
      pv0 = __builtin_amdgcn_mfma_f32_16x16x32_bf16(av, vt0[kc], pv0, 0, 0, 0);
      pv1 = __builtin_amdgcn_mfma_f32_16x16x32_bf16(av, vt1[kc], pv1, 0, 0, 0);
    }
  }

  // ---- epilogue (per wave): RMSNorm + @Wo ----
  float* const nxw = nxlds + w * (16 * 36);
#pragma unroll
  for (int jj = 0; jj < 4; ++jj) {
    float ss = pv0[jj] * pv0[jj] + pv1[jj] * pv1[jj];
    ss += __shfl_xor(ss, 1);
    ss += __shfl_xor(ss, 2);
    ss += __shfl_xor(ss, 4);
    ss += __shfl_xor(ss, 8);
    const float rms = 1.0f / sqrtf(ss * (1.f / 32.f) + 1e-5f);
    nxw[(g * 4 + jj) * 36 + r15] = pv0[jj] * rms * srw[r15] * kOutScale;
    nxw[(g * 4 + jj) * 36 + 16 + r15] =
        pv1[jj] * rms * srw[16 + r15] * kOutScale;
  }
  asm volatile("s_waitcnt lgkmcnt(0)" ::: "memory");  // own-wave LDS visible

  {
    const int q2 = lane >> 2;
    const int cg = (lane & 3) * 8;
    float o[8] = {0.f, 0.f, 0.f, 0.f, 0.f, 0.f, 0.f, 0.f};
#pragma unroll
    for (int e = 0; e < 32; ++e) {
      const float nv = nxw[q2 * 36 + e];
#pragma unroll
      for (int j = 0; j < 8; ++j) o[j] += nv * sWo[e][cg + j];
    }
    f32x4 olo = {o[0], o[1], o[2], o[3]};
    f32x4 ohi = {o[4], o[5], o[6], o[7]};
    *(f32x4*)&out[((size_t)(wrow + q2)) * 32 + cg] = olo;
    *(f32x4*)&out[((size_t)(wrow + q2)) * 32 + cg + 4] = ohi;
  }
}

}  // namespace

extern "C" void kernel_launch(void* const* d_in, const int* in_sizes, int n_in,
                              void* d_out, int out_size, void* d_ws,
                              size_t ws_size, hipStream_t stream) {
  const float* query = (const float*)d_in[0];
  const float* key = (const float*)d_in[1];
  const void* qmask = d_in[2];
  const void* kmask = d_in[3];
  const float* Wq = (const float*)d_in[4];
  const float* Wk = (const float*)d_in[5];
  const float* Wv = (const float*)d_in[6];
  const float* Wo = (const float*)d_in[7];
  const float* lq1 = (const float*)d_in[8];
  const float* lk1 = (const float*)d_in[9];
  const float* lq2 = (const float*)d_in[10];
  const float* lk2 = (const float*)d_in[11];
  const float* rmsw = (const float*)d_in[12];

  unsigned short* Kbf = (unsigned short*)d_ws;            // [B*S,32]
  unsigned short* Vt = Kbf + (size_t)kB * kS * 32;        // [B,32,S]
  unsigned short* WkT = Vt + (size_t)kB * kS * 32;        // [32,768]
  unsigned short* WvT = WkT + (size_t)32 * 768;           // [32,768]
  int* mflag = (int*)(WvT + (size_t)32 * 768);

  float* outp = (float*)d_out;
  float* diffp = outp + (size_t)kB * kL * 32;

  prep_kernel<<<dim3(193), dim3(256), 0, stream>>>(
      Wk, Wv, (const unsigned char*)qmask, WkT, WvT, mflag);
  proj_kv_kernel<<<dim3(kB * kS / 32), dim3(256), 0, stream>>>(key, WkT, WvT,
                                                               Kbf, Vt);
  attn_kernel<<<dim3(kB * (kL / 128)), dim3(512), 81920, stream>>>(
      query, Wq, Kbf, Vt, qmask, kmask, lq1, lk1, lq2, lk2, rmsw, Wo, mflag,
      outp, diffp);
}

// Round 21
// 94.939 us; speedup vs baseline: 4.6358x; 1.0477x over previous
//
#include <hip/hip_runtime.h>

namespace {

typedef __attribute__((ext_vector_type(8))) short short8v;
typedef __attribute__((ext_vector_type(4))) float f32x4;
typedef __attribute__((ext_vector_type(4))) unsigned int uint4v;

constexpr int kB = 8;
constexpr int kS = 1024;
constexpr int kSUB = 768;
constexpr int kL = 4096;                                   // P*G
constexpr float kQScale = 0.25f * 1.44269504088896340736f; // SCALING*log2(e)
constexpr float kLamInit = 0.2f;
constexpr float kOutScale = 0.8f;

__device__ __forceinline__ unsigned short f2bf(float x) {
  unsigned u = __float_as_uint(x);
  return (unsigned short)((u + 0x7FFFu + ((u >> 16) & 1u)) >> 16);
}

__device__ __forceinline__ float fast_exp2(float x) {
#if __has_builtin(__builtin_amdgcn_exp2f)
  return __builtin_amdgcn_exp2f(x);
#else
  return exp2f(x);
#endif
}

__device__ __forceinline__ int load_mask(const void* p, long i, int fmt) {
  if (fmt == 1) return (int)((const unsigned char*)p)[i];
  if (fmt == 2) return (int)(((const int*)p)[2 * i] != 0);
  return ((const int*)p)[i];
}

// ---------------------------------------------------------------------------
// prep: blocks 0..191 transpose Wk/Wv to bf16 [c][k]; block 192 detects mask
// layout (0=int32,1=u8,2=int64).
// ---------------------------------------------------------------------------
__global__ __launch_bounds__(256) void prep_kernel(
    const float* __restrict__ Wk, const float* __restrict__ Wv,
    const unsigned char* __restrict__ qm, unsigned short* __restrict__ WkT,
    unsigned short* __restrict__ WvT, int* __restrict__ flag) {
  if (blockIdx.x < 192) {
    int idx = blockIdx.x * 256 + threadIdx.x;
    if (idx < 24576) {
      const int k = idx >> 5, c = idx & 31;
      WkT[c * 768 + k] = f2bf(Wk[idx]);
    } else {
      idx -= 24576;
      const int k = idx >> 5, c = idx & 31;
      WvT[c * 768 + k] = f2bf(Wv[idx]);
    }
  } else {
    __shared__ int any14, any47;
    if (threadIdx.x == 0) { any14 = 0; any47 = 0; }
    __syncthreads();
    int l14 = 0, l47 = 0;
    for (int i = threadIdx.x; i < 16384; i += 256) {
      const unsigned char v = qm[i];
      if (v && (i & 3)) l14 = 1;
      if (v && ((i & 7) >= 4)) l47 = 1;
    }
    if (l14) atomicOr(&any14, 1);
    if (l47) atomicOr(&any47, 1);
    __syncthreads();
    if (threadIdx.x == 0) *flag = any14 ? 1 : (any47 ? 0 : 2);
  }
}

// ---------------------------------------------------------------------------
// K/V projection, split-K: 32 rows/block, 256 threads (4 waves).
// ---------------------------------------------------------------------------
__global__ __launch_bounds__(256) void proj_kv_kernel(
    const float* __restrict__ key, const unsigned short* __restrict__ WkT,
    const unsigned short* __restrict__ WvT, unsigned short* __restrict__ Kbf,
    unsigned short* __restrict__ Vt) {
  __shared__ float comb[2][64][20];
  const int t = threadIdx.x;
  const int wv = t >> 6, lane = t & 63;
  const int r15 = lane & 15, g = lane >> 4;
  const int grp = wv >> 1;
  const int half = wv & 1;
  const int row = blockIdx.x * 32 + grp * 16 + r15;
  const int kbase = half * 384;
  const float* kp = &key[(size_t)row * kSUB + kbase];
  const f32x4 zf = {0.f, 0.f, 0.f, 0.f};
  f32x4 aK0 = zf, aK1 = zf, aV0 = zf, aV1 = zf;
#pragma unroll 4
  for (int ks = 0; ks < 384; ks += 32) {
    const f32x4 lo = *(const f32x4*)&kp[ks + g * 8];
    const f32x4 hi = *(const f32x4*)&kp[ks + g * 8 + 4];
    short8v a;
#pragma unroll
    for (int j = 0; j < 4; ++j) {
      a[j] = (short)f2bf(lo[j]);
      a[4 + j] = (short)f2bf(hi[j]);
    }
    const int ko = kbase + ks + g * 8;
    const short8v bk0 = *(const short8v*)&WkT[(size_t)r15 * 768 + ko];
    const short8v bk1 = *(const short8v*)&WkT[(size_t)(16 + r15) * 768 + ko];
    const short8v bv0 = *(const short8v*)&WvT[(size_t)r15 * 768 + ko];
    const short8v bv1 = *(const short8v*)&WvT[(size_t)(16 + r15) * 768 + ko];
    aK0 = __builtin_amdgcn_mfma_f32_16x16x32_bf16(a, bk0, aK0, 0, 0, 0);
    aK1 = __builtin_amdgcn_mfma_f32_16x16x32_bf16(a, bk1, aK1, 0, 0, 0);
    aV0 = __builtin_amdgcn_mfma_f32_16x16x32_bf16(a, bv0, aV0, 0, 0, 0);
    aV1 = __builtin_amdgcn_mfma_f32_16x16x32_bf16(a, bv1, aV1, 0, 0, 0);
  }
  if (half == 1) {
    *(f32x4*)&comb[grp][lane][0] = aK0;
    *(f32x4*)&comb[grp][lane][4] = aK1;
    *(f32x4*)&comb[grp][lane][8] = aV0;
    *(f32x4*)&comb[grp][lane][12] = aV1;
  }
  __syncthreads();
  if (half == 0) {
    aK0 += *(const f32x4*)&comb[grp][lane][0];
    aK1 += *(const f32x4*)&comb[grp][lane][4];
    aV0 += *(const f32x4*)&comb[grp][lane][8];
    aV1 += *(const f32x4*)&comb[grp][lane][12];
    const int orow = blockIdx.x * 32 + grp * 16 + g * 4;
#pragma unroll
    for (int jj = 0; jj < 4; ++jj) {
      const int r = orow + jj;
      Kbf[(size_t)r * 32 + r15] = f2bf(aK0[jj]);
      Kbf[(size_t)r * 32 + 16 + r15] = f2bf(aK1[jj]);
      const int bb = r >> 10, s = r & 1023;
      Vt[((size_t)bb * 32 + r15) * kS + s] = f2bf(aV0[jj]);
      Vt[((size_t)bb * 32 + 16 + r15) * kS + s] = f2bf(aV1[jj]);
    }
  }
}

// ---------------------------------------------------------------------------
// Fused attention, wave-owns-full-row (R15/R20-verified): each of 8 waves
// owns 16 q-rows over the full S=1024, in 3 passes (sum / min / diff+PV).
// All reductions in-wave shfl; ZERO barriers/atomics/cross-wave traffic in
// the worker loop. K staged once in 80KB dynamic LDS. grid = 256 = 1/CU.
// sl-loops unrolled 2x for ILP (hide LDS/TRANS latency at 2 waves/SIMD).
// ---------------------------------------------------------------------------
__global__ __launch_bounds__(512, 2) void attn_kernel(
    const float* __restrict__ query, const float* __restrict__ Wq,
    const unsigned short* __restrict__ Kbf,
    const unsigned short* __restrict__ Vt, const void* __restrict__ qmask,
    const void* __restrict__ kmask, const float* __restrict__ lq1,
    const float* __restrict__ lk1, const float* __restrict__ lq2,
    const float* __restrict__ lk2, const float* __restrict__ rmsw,
    const float* __restrict__ Wo, const int* __restrict__ mflag,
    float* __restrict__ out, float* __restrict__ diff) {
  extern __shared__ __align__(16) unsigned short kfl[];  // [1024][40] 80KB

  __shared__ __align__(16) float ubuf[5120];  // {sWq 1K + sQi 4K} | nxlds
  __shared__ __align__(16) unsigned short qlds[128][40];
  __shared__ unsigned kmp_lds[256];
  __shared__ float sWo[32][32];
  __shared__ float srw[32];
  __shared__ int qmS[128];
  __shared__ float slam;

  float* const sWq = ubuf;
  float* const sQi = ubuf + 1024;
  float* const nxlds = ubuf;  // overlays sWq/sQi after the qproj barrier

  const int t = threadIdx.x;
  const int lane = t & 63;
  const int w = t >> 6;
  const int r15 = lane & 15;
  const int g = lane >> 4;
  const int b = blockIdx.x >> 5;
  const int rowbase = b * kL + (blockIdx.x & 31) * 128;
  const int kvb = b * kS;
  const int fmt = *mflag;

  // ---- stage (once per 128 rows) ----
  if (t < 256) {
    *(f32x4*)(sWq + 4 * t) = *(const f32x4*)(Wq + 4 * t);
    *(f32x4*)(&sWo[0][0] + 4 * t) = *(const f32x4*)(Wo + 4 * t);
    const long base = (long)kvb + 4 * t;
    const unsigned m0 = load_mask(kmask, base + 0, fmt) ? 1u : 0u;
    const unsigned m1 = load_mask(kmask, base + 1, fmt) ? 1u : 0u;
    const unsigned m2 = load_mask(kmask, base + 2, fmt) ? 1u : 0u;
    const unsigned m3 = load_mask(kmask, base + 3, fmt) ? 1u : 0u;
    kmp_lds[t] = m0 | (m1 << 8) | (m2 << 16) | (m3 << 24);
  }
  *(f32x4*)(sQi + 8 * t) = *(const f32x4*)(query + (size_t)rowbase * 32 + 8 * t);
  *(f32x4*)(sQi + 8 * t + 4) =
      *(const f32x4*)(query + (size_t)rowbase * 32 + 8 * t + 4);
#pragma unroll
  for (int p = 0; p < 8; ++p) {
    const int i = t + 512 * p;  // 0..4095: (row, quarter)
    const int row = i >> 2, qtr = i & 3;
    *(short8v*)&kfl[row * 40 + qtr * 8] =
        *(const short8v*)&Kbf[((size_t)(kvb + row)) * 32 + qtr * 8];
  }
  if (t < 128) qmS[t] = load_mask(qmask, (long)rowbase + t, fmt);
  if (t < 32) srw[t] = rmsw[t];
  if (t == 0) {
    float a = 0.f, c2 = 0.f;
#pragma unroll
    for (int i = 0; i < 16; ++i) {
      a += lq1[i] * lk1[i];
      c2 += lq2[i] * lk2[i];
    }
    slam = expf(a) - expf(c2) + kLamInit;
  }
  __syncthreads();

  // ---- fused Q projection: qlds[q][e] = bf16(dot * scale), 128 rows ----
#pragma unroll
  for (int p = 0; p < 8; ++p) {
    const int idx = t + 512 * p;
    const int row = idx >> 5, col = idx & 31;
    float a = 0.f;
#pragma unroll
    for (int k = 0; k < 32; ++k) a += sQi[row * 32 + k] * sWq[k * 32 + col];
    qlds[row][col] = f2bf(a * kQScale);
  }
  __syncthreads();  // last barrier; worker loop below is barrier-free

  const short8v z8 = {0, 0, 0, 0, 0, 0, 0, 0};
  const f32x4 zf = {0.f, 0.f, 0.f, 0.f};
  const float lam = slam;
  const int qm = qmS[w * 16 + r15];
  const int wrow = rowbase + w * 16;  // this wave's first q-row

  short8v qa0 = z8, qa1 = z8;
  if (lane < 32) {
    qa0 = *(const short8v*)&qlds[w * 16 + r15][g * 8];
    qa1 = *(const short8v*)&qlds[w * 16 + r15][16 + g * 8];
  }

  // ---- PASS A: sum of exp2(score) per (q,head), full S (no shift:
  // softmax ratios cancel; |score| << 120 so exp2 cannot overflow) ----
  f32x4 s0v = zf, s1v = zf;
#pragma unroll 2
  for (int sl = 0; sl < 8; ++sl) {
#pragma unroll
    for (int c = 0; c < 8; ++c) {
      const int srow = sl * 128 + c * 16 + r15;
      short8v kb0 = z8, kb1 = z8;
      if (lane < 32) {
        kb0 = *(const short8v*)&kfl[srow * 40 + g * 8];
        kb1 = *(const short8v*)&kfl[srow * 40 + 16 + g * 8];
      }
      const f32x4 a0 =
          __builtin_amdgcn_mfma_f32_16x16x32_bf16(kb0, qa0, zf, 0, 0, 0);
      const f32x4 a1 =
          __builtin_amdgcn_mfma_f32_16x16x32_bf16(kb1, qa1, zf, 0, 0, 0);
      const unsigned km = kmp_lds[sl * 32 + c * 4 + g];
#pragma unroll
      for (int jj = 0; jj < 4; ++jj) {
        const int mbit = (km >> (8 * jj)) & 1u;
        s0v[jj] += mbit ? fast_exp2(a0[jj]) : 0.f;
        s1v[jj] += mbit ? fast_exp2(a1[jj]) : 0.f;
      }
    }
  }
  float s0 = (s0v[0] + s0v[1]) + (s0v[2] + s0v[3]);
  float s1 = (s1v[0] + s1v[1]) + (s1v[2] + s1v[3]);
  s0 += __shfl_xor(s0, 16);
  s0 += __shfl_xor(s0, 32);
  s1 += __shfl_xor(s1, 16);
  s1 += __shfl_xor(s1, 32);
  const float f0 = 1.f / (s0 + 1e-37f);
  const float nf1 = -lam / (s1 + 1e-37f);

  // ---- PASS B: row min of d ----
  f32x4 dmn = {3.0e38f, 3.0e38f, 3.0e38f, 3.0e38f};
#pragma unroll 2
  for (int sl = 0; sl < 8; ++sl) {
#pragma unroll
    for (int c = 0; c < 8; ++c) {
      const int srow = sl * 128 + c * 16 + r15;
      short8v kb0 = z8, kb1 = z8;
      if (lane < 32) {
        kb0 = *(const short8v*)&kfl[srow * 40 + g * 8];
        kb1 = *(const short8v*)&kfl[srow * 40 + 16 + g * 8];
      }
      const f32x4 a0 =
          __builtin_amdgcn_mfma_f32_16x16x32_bf16(kb0, qa0, zf, 0, 0, 0);
      const f32x4 a1 =
          __builtin_amdgcn_mfma_f32_16x16x32_bf16(kb1, qa1, zf, 0, 0, 0);
      const unsigned km = kmp_lds[sl * 32 + c * 4 + g];
#pragma unroll
      for (int jj = 0; jj < 4; ++jj) {
        const int mbit = (km >> (8 * jj)) & 1u;
        const float e0 = mbit ? fast_exp2(a0[jj]) : 0.f;
        const float e1 = mbit ? fast_exp2(a1[jj]) : 0.f;
        dmn[jj] = fminf(dmn[jj], fmaf(e0, f0, nf1 * e1));
      }
    }
  }
  float dm = fminf(fminf(dmn[0], dmn[1]), fminf(dmn[2], dmn[3]));
  dm = fminf(dm, __shfl_xor(dm, 16));
  dm = fminf(dm, __shfl_xor(dm, 32));
  const float rme = dm - 1e-5f;  // rmin - eps

  // ---- PASS C: diff stores + PV (register-chained MFMA accumulate) ----
  f32x4 pv0 = zf, pv1 = zf;
  const int sl0 = ((g & 1) << 5) + r15;  // PV gather source lanes
  const int sl1 = sl0 + 16;
  const bool hi = (g >> 1) != 0;
#pragma unroll 2
  for (int sl = 0; sl < 8; ++sl) {
    short8v vt0[4], vt1[4];
#pragma unroll
    for (int kc = 0; kc < 4; ++kc) {
      const int soff = sl * 128 + kc * 32 + g * 8;
      vt0[kc] = *(const short8v*)&Vt[((size_t)(b * 32 + r15)) * kS + soff];
      vt1[kc] = *(const short8v*)&Vt[((size_t)(b * 32 + 16 + r15)) * kS + soff];
    }
    unsigned pkx[8], pky[8];
#pragma unroll
    for (int c = 0; c < 8; ++c) {
      const int srow = sl * 128 + c * 16 + r15;
      short8v kb0 = z8, kb1 = z8;
      if (lane < 32) {
        kb0 = *(const short8v*)&kfl[srow * 40 + g * 8];
        kb1 = *(const short8v*)&kfl[srow * 40 + 16 + g * 8];
      }
      const f32x4 a0 =
          __builtin_amdgcn_mfma_f32_16x16x32_bf16(kb0, qa0, zf, 0, 0, 0);
      const f32x4 a1 =
          __builtin_amdgcn_mfma_f32_16x16x32_bf16(kb1, qa1, zf, 0, 0, 0);
      const unsigned km = kmp_lds[sl * 32 + c * 4 + g];
      f32x4 fd;
#pragma unroll
      for (int jj = 0; jj < 4; ++jj) {
        const int mbit = (km >> (8 * jj)) & 1u;
        const float e0 = mbit ? fast_exp2(a0[jj]) : 0.f;
        const float e1 = mbit ? fast_exp2(a1[jj]) : 0.f;
        const float d = fmaf(e0, f0, nf1 * e1);
        fd[jj] = (qm && mbit) ? d - rme : 0.f;
      }
      pkx[c] = (unsigned)f2bf(fd[0]) | ((unsigned)f2bf(fd[1]) << 16);
      pky[c] = (unsigned)f2bf(fd[2]) | ((unsigned)f2bf(fd[3]) << 16);
      *(f32x4*)&diff[((size_t)(wrow + r15)) * kS + sl * 128 + c * 16 + g * 4] =
          fd;
    }
    // PV gather: broadcast both chunk parities; DEST selects with hi
#pragma unroll
    for (int kc = 0; kc < 4; ++kc) {
      const unsigned x0a = (unsigned)__shfl((int)pkx[2 * kc], sl0);
      const unsigned y0a = (unsigned)__shfl((int)pky[2 * kc], sl0);
      const unsigned x0b = (unsigned)__shfl((int)pkx[2 * kc], sl1);
      const unsigned y0b = (unsigned)__shfl((int)pky[2 * kc], sl1);
      const unsigned x1a = (unsigned)__shfl((int)pkx[2 * kc + 1], sl0);
      const unsigned y1a = (unsigned)__shfl((int)pky[2 * kc + 1], sl0);
      const unsigned x1b = (unsigned)__shfl((int)pkx[2 * kc + 1], sl1);
      const unsigned y1b = (unsigned)__shfl((int)pky[2 * kc + 1], sl1);
      uint4v avw;
      avw.x = hi ? x1a : x0a;
      avw.y = hi ? y1a : y0a;
      avw.z = hi ? x1b : x0b;
      avw.w = hi ? y1b : y0b;
      const short8v av = *(const short8v*)&avw;
      pv0 = __builtin_amdgcn_mfma_f32_16x16x32_bf16(av, vt0[kc], pv0, 0, 0, 0);
      pv1 = __builtin_amdgcn_mfma_f32_16x16x32_bf16(av, vt1[kc], pv1, 0, 0, 0);
    }
  }

  // ---- epilogue (per wave): RMSNorm + @Wo ----
  float* const nxw = nxlds + w * (16 * 36);
#pragma unroll
  for (int jj = 0; jj < 4; ++jj) {
    float ss = pv0[jj] * pv0[jj] + pv1[jj] * pv1[jj];
    ss += __shfl_xor(ss, 1);
    ss += __shfl_xor(ss, 2);
    ss += __shfl_xor(ss, 4);
    ss += __shfl_xor(ss, 8);
    const float rms = 1.0f / sqrtf(ss * (1.f / 32.f) + 1e-5f);
    nxw[(g * 4 + jj) * 36 + r15] = pv0[jj] * rms * srw[r15] * kOutScale;
    nxw[(g * 4 + jj) * 36 + 16 + r15] =
        pv1[jj] * rms * srw[16 + r15] * kOutScale;
  }
  asm volatile("s_waitcnt lgkmcnt(0)" ::: "memory");  // own-wave LDS visible

  {
    const int q2 = lane >> 2;
    const int cg = (lane & 3) * 8;
    float o[8] = {0.f, 0.f, 0.f, 0.f, 0.f, 0.f, 0.f, 0.f};
#pragma unroll
    for (int e = 0; e < 32; ++e) {
      const float nv = nxw[q2 * 36 + e];
#pragma unroll
      for (int j = 0; j < 8; ++j) o[j] += nv * sWo[e][cg + j];
    }
    f32x4 olo = {o[0], o[1], o[2], o[3]};
    f32x4 ohi = {o[4], o[5], o[6], o[7]};
    *(f32x4*)&out[((size_t)(wrow + q2)) * 32 + cg] = olo;
    *(f32x4*)&out[((size_t)(wrow + q2)) * 32 + cg + 4] = ohi;
  }
}

}  // namespace

extern "C" void kernel_launch(void* const* d_in, const int* in_sizes, int n_in,
                              void* d_out, int out_size, void* d_ws,
                              size_t ws_size, hipStream_t stream) {
  const float* query = (const float*)d_in[0];
  const float* key = (const float*)d_in[1];
  const void* qmask = d_in[2];
  const void* kmask = d_in[3];
  const float* Wq = (const float*)d_in[4];
  const float* Wk = (const float*)d_in[5];
  const float* Wv = (const float*)d_in[6];
  const float* Wo = (const float*)d_in[7];
  const float* lq1 = (const float*)d_in[8];
  const float* lk1 = (const float*)d_in[9];
  const float* lq2 = (const float*)d_in[10];
  const float* lk2 = (const float*)d_in[11];
  const float* rmsw = (const float*)d_in[12];

  unsigned short* Kbf = (unsigned short*)d_ws;            // [B*S,32]
  unsigned short* Vt = Kbf + (size_t)kB * kS * 32;        // [B,32,S]
  unsigned short* WkT = Vt + (size_t)kB * kS * 32;        // [32,768]
  unsigned short* WvT = WkT + (size_t)32 * 768;           // [32,768]
  int* mflag = (int*)(WvT + (size_t)32 * 768);

  float* outp = (float*)d_out;
  float* diffp = outp + (size_t)kB * kL * 32;

  prep_kernel<<<dim3(193), dim3(256), 0, stream>>>(
      Wk, Wv, (const unsigned char*)qmask, WkT, WvT, mflag);
  proj_kv_kernel<<<dim3(kB * kS / 32), dim3(256), 0, stream>>>(key, WkT, WvT,
                                                               Kbf, Vt);
  attn_kernel<<<dim3(kB * (kL / 128)), dim3(512), 81920, stream>>>(
      query, Wq, Kbf, Vt, qmask, kmask, lq1, lk1, lq2, lk2, rmsw, Wo, mflag,
      outp, diffp);
}